// Round 1
// baseline (16197.530 us; speedup 1.0000x reference)
//
#include <hip/hip_runtime.h>
#include <math.h>

#define HW 9216   // 96*96

__device__ __forceinline__ float sigmoidf_(float x) { return 1.0f / (1.0f + expf(-x)); }

// ---------------------------------------------------------------------------
// Kernel A: i2h = conv3x3(x_t, 8->192, pad1) + bias  -> ws_i2h (B,192,HW)
// grid (36, 192, 4), block 256. o = blockIdx.y (scalar => weight s_loads).
// ---------------------------------------------------------------------------
__global__ __launch_bounds__(256) void k_i2h(
    const float* __restrict__ inp, int t,
    const float* __restrict__ w, const float* __restrict__ bias,
    float* __restrict__ out)
{
  const int p = blockIdx.x * 256 + threadIdx.x;   // 0..9215
  const int o = blockIdx.y;
  const int b = blockIdx.z;
  const int y = p / 96, x = p % 96;
  const float* xin = inp + ((size_t)(b * 10 + t)) * 8 * HW;
  float acc = bias[o];
  for (int ci = 0; ci < 8; ++ci) {
    const float* xc = xin + (size_t)ci * HW;
    const float* wc = w + ((size_t)o * 8 + ci) * 9;
    #pragma unroll
    for (int ky = 0; ky < 3; ++ky) {
      int yy = y + ky - 1;
      if (yy < 0 || yy >= 96) continue;
      #pragma unroll
      for (int kx = 0; kx < 3; ++kx) {
        int xx = x + kx - 1;
        if (xx < 0 || xx >= 96) continue;
        acc += wc[ky * 3 + kx] * xc[yy * 96 + xx];
      }
    }
  }
  out[((size_t)(b * 192 + o)) * HW + p] = acc;
}

// ---------------------------------------------------------------------------
// Kernel B: f = tanh(conv5x5(x_t, 8->32) + conv5x5(h, 64->32) + biases)
// grid (48, 4, 4), block 192 (2 rows x 96 cols). og=blockIdx.y -> 8 o each.
// Stages one input channel (6 rows x 96) in LDS per iteration.
// ---------------------------------------------------------------------------
__global__ __launch_bounds__(192) void k_f(
    const float* __restrict__ inp, int t,
    const float* __restrict__ hbase, long long hstr,
    const float* __restrict__ wi, const float* __restrict__ bi,
    const float* __restrict__ wh, const float* __restrict__ bh,
    float* __restrict__ fout)
{
  __shared__ float tile[6 * 96];
  const int tid = threadIdx.x;
  const int r0 = blockIdx.x * 2;
  const int og = blockIdx.y;   // 0..3
  const int b  = blockIdx.z;
  const int ly = tid / 96, lx = tid % 96;
  const int y = r0 + ly;
  float acc[8];
  #pragma unroll
  for (int i = 0; i < 8; ++i) acc[i] = bi[og * 8 + i] + bh[og * 8 + i];
  const float* xin = inp + ((size_t)(b * 10 + t)) * 8 * HW;
  const float* hb  = hbase + (size_t)b * hstr;

  for (int ci = 0; ci < 72; ++ci) {
    const float* src = (ci < 8) ? (xin + (size_t)ci * HW)
                                : (hb + (size_t)(ci - 8) * HW);
    __syncthreads();
    for (int i = tid; i < 576; i += 192) {
      int rr = r0 - 2 + i / 96;
      tile[i] = (rr >= 0 && rr < 96) ? src[rr * 96 + (i % 96)] : 0.0f;
    }
    __syncthreads();
    const float* wbase = (ci < 8) ? (wi + ((size_t)(og * 8) * 8 + ci) * 25)
                                  : (wh + ((size_t)(og * 8) * 64 + (ci - 8)) * 25);
    const int wstride = (ci < 8) ? 8 * 25 : 64 * 25;
    #pragma unroll
    for (int ky = 0; ky < 5; ++ky) {
      #pragma unroll
      for (int kx = 0; kx < 5; ++kx) {
        int xx = lx + kx - 2;
        float v = (xx >= 0 && xx < 96) ? tile[(ly + ky) * 96 + xx] : 0.0f;
        #pragma unroll
        for (int i = 0; i < 8; ++i)
          acc[i] += wbase[(size_t)i * wstride + ky * 5 + kx] * v;
      }
    }
  }
  float* fo = fout + (size_t)b * 32 * HW + (size_t)y * 96 + lx;
  #pragma unroll
  for (int i = 0; i < 8; ++i)
    fo[(size_t)(og * 8 + i) * HW] = tanhf(acc[i]);
}

// ---------------------------------------------------------------------------
// Kernel C: flows = conv5x5(f, 32->26) + bias -> ws_fl (B,26,HW)
// grid (48, 2, 4), block 192. og -> 13 o each.
// ---------------------------------------------------------------------------
__global__ __launch_bounds__(192) void k_flows(
    const float* __restrict__ f,
    const float* __restrict__ w, const float* __restrict__ bias,
    float* __restrict__ flout)
{
  __shared__ float tile[6 * 96];
  const int tid = threadIdx.x;
  const int r0 = blockIdx.x * 2;
  const int og = blockIdx.y;   // 0..1
  const int b  = blockIdx.z;
  const int ly = tid / 96, lx = tid % 96;
  const int y = r0 + ly;
  float acc[13];
  #pragma unroll
  for (int i = 0; i < 13; ++i) acc[i] = bias[og * 13 + i];
  const float* fb = f + (size_t)b * 32 * HW;

  for (int ci = 0; ci < 32; ++ci) {
    __syncthreads();
    for (int i = tid; i < 576; i += 192) {
      int rr = r0 - 2 + i / 96;
      tile[i] = (rr >= 0 && rr < 96) ? fb[(size_t)ci * HW + rr * 96 + (i % 96)] : 0.0f;
    }
    __syncthreads();
    #pragma unroll
    for (int ky = 0; ky < 5; ++ky) {
      #pragma unroll
      for (int kx = 0; kx < 5; ++kx) {
        int xx = lx + kx - 2;
        float v = (xx >= 0 && xx < 96) ? tile[(ly + ky) * 96 + xx] : 0.0f;
        #pragma unroll
        for (int i = 0; i < 13; ++i)
          acc[i] += w[(((size_t)(og * 13 + i)) * 32 + ci) * 25 + ky * 5 + kx] * v;
      }
    }
  }
  float* fo = flout + (size_t)b * 26 * HW + (size_t)y * 96 + lx;
  #pragma unroll
  for (int i = 0; i < 13; ++i)
    fo[(size_t)(og * 13 + i) * HW] = acc[i];
}

__device__ __forceinline__ float bilin_(const float* __restrict__ hc,
                                        int o00, int o01, int o10, int o11,
                                        float w00, float w01, float w10, float w11)
{
  float s = 0.0f;
  if (o00 >= 0) s += w00 * hc[o00];
  if (o01 >= 0) s += w01 * hc[o01];
  if (o10 >= 0) s += w10 * hc[o10];
  if (o11 >= 0) s += w11 * hc[o11];
  return s;
}

// ---------------------------------------------------------------------------
// Kernel D: fused 13-way bilinear warp of h + 1x1 conv (832->192) + gates.
// grid (144, 4), block 256 = 64 pixels x 4 wave-aligned o-groups (48 o each).
// Per l: all 64 h-channels x 64 pixels gathered into LDS (layout
// [cquad][pixel][4] -> conflict-free float4), then accumulate with
// scalarized (s_load) weight reads: v_fmac vacc, s_w, v_v.
// ---------------------------------------------------------------------------
__global__ __launch_bounds__(256) void k_fused(
    const float* __restrict__ flows,           // (B,26,HW)
    const float* __restrict__ hbase, long long hstr,
    const float* __restrict__ i2h,             // (B,192,HW)
    const float* __restrict__ ww,              // (192,832)
    const float* __restrict__ wb,              // (192)
    float* __restrict__ outb, long long ostr,  // outputs[:,t] base, per-b stride
    float* __restrict__ lastb)                 // h_last base or nullptr
{
  __shared__ __align__(16) float smem[12288];  // 48 KB: warped (first 16KB) then h2h
  const int tid = threadIdx.x;
  const int pp  = tid & 63;
  const int og  = tid >> 6;                                  // wave-uniform
  const int og_s = __builtin_amdgcn_readfirstlane(og);       // force SGPR
  const int b   = blockIdx.y;
  const int p   = blockIdx.x * 64 + pp;
  const int ypix = p / 96, xpix = p % 96;
  const float* hb  = hbase + (size_t)b * hstr;
  const float* flb = flows + (size_t)b * 26 * HW;

  float acc[48];
  #pragma unroll
  for (int j = 0; j < 48; ++j) acc[j] = wb[og_s * 48 + j];

  for (int l = 0; l < 13; ++l) {
    // --- per-pixel coords (recomputed by each o-group; cheap) ---
    float fx = flb[(size_t)(2 * l) * HW + p];
    float fy = flb[(size_t)(2 * l + 1) * HW + p];
    float vx = (float)xpix - fx;
    float vy = (float)ypix - fy;
    float gxn = 2.0f * vx / 96.0f - 1.0f;
    float gyn = 2.0f * vy / 96.0f - 1.0f;
    float ix = ((gxn + 1.0f) * 96.0f - 1.0f) * 0.5f;
    float iy = ((gyn + 1.0f) * 96.0f - 1.0f) * 0.5f;
    float x0f = floorf(ix), y0f = floorf(iy);
    float wx1 = ix - x0f, wy1 = iy - y0f;
    float wx0 = 1.0f - wx1, wy0 = 1.0f - wy1;
    int x0 = (int)x0f, y0 = (int)y0f;
    bool vx0 = (x0 >= 0) && (x0 < 96);
    bool vx1 = (x0 + 1 >= 0) && (x0 + 1 < 96);
    bool vy0g = (y0 >= 0) && (y0 < 96);
    bool vy1g = (y0 + 1 >= 0) && (y0 + 1 < 96);
    int o00 = (vx0 && vy0g) ? (y0 * 96 + x0)           : -1;
    int o01 = (vx1 && vy0g) ? (y0 * 96 + x0 + 1)       : -1;
    int o10 = (vx0 && vy1g) ? ((y0 + 1) * 96 + x0)     : -1;
    int o11 = (vx1 && vy1g) ? ((y0 + 1) * 96 + x0 + 1) : -1;
    float w00 = wy0 * wx0, w01 = wy0 * wx1, w10 = wy1 * wx0, w11 = wy1 * wx1;

    __syncthreads();   // warped region free (prev accumulate done)
    // --- gather: this thread covers c-quads og*4 .. og*4+3 at pixel pp ---
    #pragma unroll
    for (int k = 0; k < 4; ++k) {
      int cq = og * 4 + k;   // 0..15
      float4 v;
      v.x = bilin_(hb + (size_t)(cq * 4 + 0) * HW, o00, o01, o10, o11, w00, w01, w10, w11);
      v.y = bilin_(hb + (size_t)(cq * 4 + 1) * HW, o00, o01, o10, o11, w00, w01, w10, w11);
      v.z = bilin_(hb + (size_t)(cq * 4 + 2) * HW, o00, o01, o10, o11, w00, w01, w10, w11);
      v.w = bilin_(hb + (size_t)(cq * 4 + 3) * HW, o00, o01, o10, o11, w00, w01, w10, w11);
      *(float4*)&smem[cq * 256 + pp * 4] = v;
    }
    __syncthreads();
    // --- accumulate: acc[j] += sum_c ww[og*48+j][l*64+c] * warped[c][pp] ---
    const float* wl = ww + (size_t)og_s * 48 * 832 + l * 64;
    #pragma unroll 2
    for (int cc = 0; cc < 16; ++cc) {
      float4 vv = *(const float4*)&smem[cc * 256 + pp * 4];
      #pragma unroll
      for (int j = 0; j < 48; ++j) {
        const float4 wv = *(const float4*)(wl + (size_t)j * 832 + cc * 4);
        acc[j] += wv.x * vv.x + wv.y * vv.y + wv.z * vv.z + wv.w * vv.w;
      }
    }
  }

  __syncthreads();
  #pragma unroll
  for (int j = 0; j < 48; ++j) smem[(og * 48 + j) * 64 + pp] = acc[j];
  __syncthreads();

  // --- gates: thread handles channels c = og + 4k, k=0..15, at pixel pp ---
  const float* i2hb = i2h + (size_t)b * 192 * HW + p;
  float* ob = outb + (size_t)b * ostr;
  #pragma unroll
  for (int k = 0; k < 16; ++k) {
    int c = og + k * 4;
    float rh = smem[c * 64 + pp];
    float uh = smem[(64 + c) * 64 + pp];
    float nh = smem[(128 + c) * 64 + pp];
    float rt = i2hb[(size_t)c * HW];
    float ut = i2hb[(size_t)(64 + c) * HW];
    float nt = i2hb[(size_t)(128 + c) * HW];
    float r = sigmoidf_(rt + rh);
    float u = sigmoidf_(ut + uh);
    float n = sigmoidf_(nt + r * nh);
    float hp = hb[(size_t)c * HW + p];
    float hn = (1.0f - u) * n + u * hp;
    ob[(size_t)c * HW + p] = hn;
    if (lastb) lastb[((size_t)b * 64 + c) * HW + p] = hn;
  }
}

// ---------------------------------------------------------------------------
extern "C" void kernel_launch(void* const* d_in, const int* in_sizes, int n_in,
                              void* d_out, int out_size, void* d_ws, size_t ws_size,
                              hipStream_t stream)
{
  const float* inp   = (const float*)d_in[0];
  const float* state = (const float*)d_in[1];
  const float* i2h_w = (const float*)d_in[2];
  const float* i2h_b = (const float*)d_in[3];
  const float* i2f_w = (const float*)d_in[4];
  const float* i2f_b = (const float*)d_in[5];
  const float* h2f_w = (const float*)d_in[6];
  const float* h2f_b = (const float*)d_in[7];
  const float* fl_w  = (const float*)d_in[8];
  const float* fl_b  = (const float*)d_in[9];
  const float* wr_w  = (const float*)d_in[10];
  const float* wr_b  = (const float*)d_in[11];
  float* out = (float*)d_out;
  float* ws  = (float*)d_ws;

  // ws layout (floats): i2h 4*192*9216 | f 4*32*9216 | flows 4*26*9216  (~37 MB)
  float* ws_i2h = ws;
  float* ws_f   = ws + 7077888;
  float* ws_fl  = ws + 7077888 + 1179648;

  const long long OB = (long long)10 * 64 * HW;  // outputs per-batch stride

  for (int t = 0; t < 10; ++t) {
    const float* hbase = (t == 0) ? state : (out + (size_t)(t - 1) * 64 * HW);
    long long hstr = (t == 0) ? (long long)64 * HW : OB;

    k_i2h<<<dim3(36, 192, 4), 256, 0, stream>>>(inp, t, i2h_w, i2h_b, ws_i2h);
    k_f<<<dim3(48, 4, 4), 192, 0, stream>>>(inp, t, hbase, hstr,
                                            i2f_w, i2f_b, h2f_w, h2f_b, ws_f);
    k_flows<<<dim3(48, 2, 4), 192, 0, stream>>>(ws_f, fl_w, fl_b, ws_fl);

    float* outbase = out + (size_t)t * 64 * HW;
    float* lastb = (t == 9) ? (out + (size_t)4 * 10 * 64 * HW) : nullptr;
    k_fused<<<dim3(144, 4), 256, 0, stream>>>(ws_fl, hbase, hstr, ws_i2h,
                                              wr_w, wr_b, outbase, OB, lastb);
  }
}

// Round 2
// 10940.218 us; speedup vs baseline: 1.4805x; 1.4805x over previous
//
#include <hip/hip_runtime.h>
#include <math.h>

#define HW 9216   // 96*96

typedef __attribute__((ext_vector_type(8))) short short8;
typedef __attribute__((ext_vector_type(4))) float float4v;

__device__ __forceinline__ float sigmoidf_(float x) { return 1.0f / (1.0f + expf(-x)); }

// round-to-nearest-even fp32 -> bf16 (as raw short)
__device__ __forceinline__ short bf16rne(float f) {
  unsigned u = __builtin_bit_cast(unsigned, f);
  unsigned r = (u + 0x7FFFu + ((u >> 16) & 1u)) >> 16;
  return (short)r;
}

// ---------------------------------------------------------------------------
// Kernel W: convert wrap_w (192,832) fp32 -> bf16, layout [l][n][c] (l=13,n=192,c=64)
// ---------------------------------------------------------------------------
__global__ __launch_bounds__(256) void k_wconv(const float* __restrict__ w,
                                               short* __restrict__ o)
{
  int i = blockIdx.x * 256 + threadIdx.x;   // over 192*832
  if (i >= 192 * 832) return;
  int n = i / 832, k = i % 832;
  int l = k >> 6, c = k & 63;
  o[((size_t)l * 192 + n) * 64 + c] = bf16rne(w[i]);
}

// ---------------------------------------------------------------------------
// Kernel A: i2h = conv3x3(x_t, 8->192, pad1) + bias  -> ws_i2h (B,192,HW)
// grid (36, 48, 4), block 256. 4 outputs per block (input taps reused x4).
// ---------------------------------------------------------------------------
__global__ __launch_bounds__(256) void k_i2h(
    const float* __restrict__ inp, int t,
    const float* __restrict__ w, const float* __restrict__ bias,
    float* __restrict__ out)
{
  const int p  = blockIdx.x * 256 + threadIdx.x;   // 0..9215
  const int og = blockIdx.y;                       // 0..47 -> o = og*4 + i
  const int b  = blockIdx.z;
  const int y = p / 96, x = p % 96;
  const float* xin = inp + ((size_t)(b * 10 + t)) * 8 * HW;
  float acc[4];
  #pragma unroll
  for (int i = 0; i < 4; ++i) acc[i] = bias[og * 4 + i];
  for (int ci = 0; ci < 8; ++ci) {
    const float* xc = xin + (size_t)ci * HW;
    float v[9];
    #pragma unroll
    for (int ky = 0; ky < 3; ++ky) {
      int yy = y + ky - 1;
      bool vy = (yy >= 0) && (yy < 96);
      #pragma unroll
      for (int kx = 0; kx < 3; ++kx) {
        int xx = x + kx - 1;
        bool ok = vy && (xx >= 0) && (xx < 96);
        v[ky * 3 + kx] = ok ? xc[yy * 96 + xx] : 0.0f;
      }
    }
    #pragma unroll
    for (int i = 0; i < 4; ++i) {
      const float* wc = w + (((size_t)(og * 4 + i)) * 8 + ci) * 9;
      #pragma unroll
      for (int k = 0; k < 9; ++k) acc[i] += wc[k] * v[k];
    }
  }
  #pragma unroll
  for (int i = 0; i < 4; ++i)
    out[((size_t)(b * 192 + og * 4 + i)) * HW + p] = acc[i];
}

// ---------------------------------------------------------------------------
// Kernel B: f = tanh(conv5x5(x_t, 8->32) + conv5x5(h, 64->32) + biases)
// grid (24, 4, 4), block 192. 4 output rows/block (2 px/thread), input
// channels staged in LDS 8 at a time (18 syncs vs 144).
// ---------------------------------------------------------------------------
__global__ __launch_bounds__(192) void k_f(
    const float* __restrict__ inp, int t,
    const float* __restrict__ hbase, long long hstr,
    const float* __restrict__ wi, const float* __restrict__ bi,
    const float* __restrict__ wh, const float* __restrict__ bh,
    float* __restrict__ fout)
{
  __shared__ float tile[8 * 8 * 96];   // [ci][row 0..7][col] = 24 KB
  const int tid = threadIdx.x;
  const int r0 = blockIdx.x * 4;
  const int og = blockIdx.y;   // 0..3 -> 8 outputs
  const int b  = blockIdx.z;
  const int ly = tid / 96, lx = tid % 96;
  float acc[8][2];
  #pragma unroll
  for (int i = 0; i < 8; ++i) {
    acc[i][0] = bi[og * 8 + i] + bh[og * 8 + i];
    acc[i][1] = acc[i][0];
  }
  const float* xin = inp + ((size_t)(b * 10 + t)) * 8 * HW;
  const float* hb  = hbase + (size_t)b * hstr;

  for (int cc = 0; cc < 9; ++cc) {           // 9 chunks of 8 channels
    __syncthreads();
    for (int i = tid; i < 8 * 768; i += 192) {
      int ci = i / 768, rem = i % 768;
      int rr = rem / 96, col = rem % 96;
      int grow = r0 - 2 + rr;
      int cig = cc * 8 + ci;
      const float* src = (cig < 8) ? (xin + (size_t)cig * HW)
                                   : (hb + (size_t)(cig - 8) * HW);
      tile[i] = (grow >= 0 && grow < 96) ? src[grow * 96 + col] : 0.0f;
    }
    __syncthreads();
    for (int ci = 0; ci < 8; ++ci) {
      int cig = cc * 8 + ci;
      const float* wbase = (cig < 8) ? (wi + (((size_t)(og * 8)) * 8 + cig) * 25)
                                     : (wh + (((size_t)(og * 8)) * 64 + (cig - 8)) * 25);
      const int wstride = (cig < 8) ? 8 * 25 : 64 * 25;
      #pragma unroll
      for (int ky = 0; ky < 5; ++ky) {
        #pragma unroll
        for (int kx = 0; kx < 5; ++kx) {
          int xx = lx + kx - 2;
          bool okx = (xx >= 0) && (xx < 96);
          float v0 = okx ? tile[ci * 768 + (ly + ky) * 96 + xx] : 0.0f;
          float v1 = okx ? tile[ci * 768 + (ly + 2 + ky) * 96 + xx] : 0.0f;
          #pragma unroll
          for (int i = 0; i < 8; ++i) {
            float wv = wbase[(size_t)i * wstride + ky * 5 + kx];
            acc[i][0] += wv * v0;
            acc[i][1] += wv * v1;
          }
        }
      }
    }
  }
  #pragma unroll
  for (int px = 0; px < 2; ++px) {
    int y = r0 + ly + 2 * px;
    float* fo = fout + (size_t)b * 32 * HW + (size_t)y * 96 + lx;
    #pragma unroll
    for (int i = 0; i < 8; ++i)
      fo[(size_t)(og * 8 + i) * HW] = tanhf(acc[i][px]);
  }
}

// ---------------------------------------------------------------------------
// Kernel C: flows = conv5x5(f, 32->26) + bias -> ws_fl (B,26,HW)
// grid (48, 2, 4), block 192. Channels staged 8 at a time (8 syncs vs 64).
// ---------------------------------------------------------------------------
__global__ __launch_bounds__(192) void k_flows(
    const float* __restrict__ f,
    const float* __restrict__ w, const float* __restrict__ bias,
    float* __restrict__ flout)
{
  __shared__ float tile[8 * 6 * 96];   // 18 KB
  const int tid = threadIdx.x;
  const int r0 = blockIdx.x * 2;
  const int og = blockIdx.y;   // 0..1 -> 13 outputs
  const int b  = blockIdx.z;
  const int ly = tid / 96, lx = tid % 96;
  const int y = r0 + ly;
  float acc[13];
  #pragma unroll
  for (int i = 0; i < 13; ++i) acc[i] = bias[og * 13 + i];
  const float* fb = f + (size_t)b * 32 * HW;

  for (int cc = 0; cc < 4; ++cc) {
    __syncthreads();
    for (int i = tid; i < 8 * 576; i += 192) {
      int ci = i / 576, rem = i % 576;
      int rr = rem / 96, col = rem % 96;
      int grow = r0 - 2 + rr;
      tile[i] = (grow >= 0 && grow < 96)
                  ? fb[(size_t)(cc * 8 + ci) * HW + grow * 96 + col] : 0.0f;
    }
    __syncthreads();
    for (int ci = 0; ci < 8; ++ci) {
      int cig = cc * 8 + ci;
      #pragma unroll
      for (int ky = 0; ky < 5; ++ky) {
        #pragma unroll
        for (int kx = 0; kx < 5; ++kx) {
          int xx = lx + kx - 2;
          float v = (xx >= 0 && xx < 96) ? tile[ci * 576 + (ly + ky) * 96 + xx] : 0.0f;
          #pragma unroll
          for (int i = 0; i < 13; ++i)
            acc[i] += w[(((size_t)(og * 13 + i)) * 32 + cig) * 25 + ky * 5 + kx] * v;
        }
      }
    }
  }
  float* fo = flout + (size_t)b * 26 * HW + (size_t)y * 96 + lx;
  #pragma unroll
  for (int i = 0; i < 13; ++i)
    fo[(size_t)(og * 13 + i) * HW] = acc[i];
}

__device__ __forceinline__ float bilin_(const float* __restrict__ hc,
                                        int o00, int o01, int o10, int o11,
                                        float w00, float w01, float w10, float w11)
{
  float s = 0.0f;
  if (o00 >= 0) s += w00 * hc[o00];
  if (o01 >= 0) s += w01 * hc[o01];
  if (o10 >= 0) s += w10 * hc[o10];
  if (o11 >= 0) s += w11 * hc[o11];
  return s;
}

// ---------------------------------------------------------------------------
// Kernel D: fused 13-way bilinear warp of h + 1x1 conv (832->192) via bf16
// MFMA + gates. grid (144, 4), block 256 (4 waves).
// Per l: stage bf16 weight slice (192x64) + gathered warped h (64px x 64ch)
// into LDS, then 16x16x32 bf16 MFMA. A = W (m=ch), B = V^T (n=px).
// Layouts (verified m89/m120): A[m=lane&15][k=quad*8+j],
// B[k=quad*8+j][n=lane&15], D: row m=quad*4+reg, col n=lane&15.
// ---------------------------------------------------------------------------
__global__ __launch_bounds__(256) void k_fused(
    const float* __restrict__ flows,           // (B,26,HW)
    const float* __restrict__ hbase, long long hstr,
    const float* __restrict__ i2h,             // (B,192,HW)
    const short* __restrict__ wbf,             // bf16 [13][192][64]
    const float* __restrict__ wb,              // (192)
    float* __restrict__ outb, long long ostr,
    float* __restrict__ lastb)
{
  // phase1: lds_w 192x72 bf16 (27648B) + lds_v 64x72 bf16 (9216B) = 36864B
  // phase2: h2h 192x65 fp32 = 49920B   (union)
  __shared__ __align__(16) char smem_raw[49920];
  short* lds_w = (short*)smem_raw;
  short* lds_v = lds_w + 192 * 72;
  float* lds_h = (float*)smem_raw;

  const int tid = threadIdx.x;
  const int pp  = tid & 63;        // lane (wave==64)
  const int cg  = tid >> 6;        // wave id 0..3
  const int b   = blockIdx.y;
  const int p   = blockIdx.x * 64 + pp;
  const int ypix = p / 96, xpix = p % 96;
  const float* hb  = hbase + (size_t)b * hstr;
  const float* flb = flows + (size_t)b * 26 * HW;
  const int ml = pp & 15;          // lane&15
  const int qd = pp >> 4;          // quad

  float4v acc[3][4];
  #pragma unroll
  for (int i = 0; i < 3; ++i)
    #pragma unroll
    for (int j = 0; j < 4; ++j)
      #pragma unroll
      for (int r = 0; r < 4; ++r) acc[i][j][r] = 0.0f;

  for (int l = 0; l < 13; ++l) {
    __syncthreads();   // previous iteration's LDS reads complete
    // --- stage weight slice l: [192][64] bf16 -> lds_w stride 72 ---
    {
      const short* wsrc = wbf + (size_t)l * 192 * 64;
      #pragma unroll
      for (int it = 0; it < 6; ++it) {
        int idx = tid + it * 256;          // 0..1535 chunks of 8 shorts
        int n = idx >> 3, c8 = (idx & 7) * 8;
        short8 v = *(const short8*)(wsrc + n * 64 + c8);
        *(short8*)(lds_w + n * 72 + c8) = v;
      }
    }
    // --- coords for this pixel ---
    float fx = flb[(size_t)(2 * l) * HW + p];
    float fy = flb[(size_t)(2 * l + 1) * HW + p];
    float vx = (float)xpix - fx;
    float vy = (float)ypix - fy;
    float gxn = 2.0f * vx / 96.0f - 1.0f;
    float gyn = 2.0f * vy / 96.0f - 1.0f;
    float ix = ((gxn + 1.0f) * 96.0f - 1.0f) * 0.5f;
    float iy = ((gyn + 1.0f) * 96.0f - 1.0f) * 0.5f;
    float x0f = floorf(ix), y0f = floorf(iy);
    float wx1 = ix - x0f, wy1 = iy - y0f;
    float wx0 = 1.0f - wx1, wy0 = 1.0f - wy1;
    int x0 = (int)x0f, y0 = (int)y0f;
    bool vx0 = (x0 >= 0) && (x0 < 96);
    bool vx1 = (x0 + 1 >= 0) && (x0 + 1 < 96);
    bool vy0g = (y0 >= 0) && (y0 < 96);
    bool vy1g = (y0 + 1 >= 0) && (y0 + 1 < 96);
    int o00 = (vx0 && vy0g) ? (y0 * 96 + x0)           : -1;
    int o01 = (vx1 && vy0g) ? (y0 * 96 + x0 + 1)       : -1;
    int o10 = (vx0 && vy1g) ? ((y0 + 1) * 96 + x0)     : -1;
    int o11 = (vx1 && vy1g) ? ((y0 + 1) * 96 + x0 + 1) : -1;
    float w00 = wy0 * wx0, w01 = wy0 * wx1, w10 = wy1 * wx0, w11 = wy1 * wx1;

    // --- gather 16 channels (cg*16..+15) for pixel pp -> lds_v[pp][ch] ---
    short vv[16];
    #pragma unroll
    for (int k = 0; k < 16; ++k) {
      int c = cg * 16 + k;
      float s = bilin_(hb + (size_t)c * HW, o00, o01, o10, o11, w00, w01, w10, w11);
      vv[k] = bf16rne(s);
    }
    *(short8*)(lds_v + pp * 72 + cg * 16)     = *(short8*)&vv[0];
    *(short8*)(lds_v + pp * 72 + cg * 16 + 8) = *(short8*)&vv[8];
    __syncthreads();

    // --- MFMA: wave cg owns out-channels [48cg, 48cg+48) x 64 px ---
    #pragma unroll
    for (int ks = 0; ks < 2; ++ks) {
      short8 af[3], bfr[4];
      #pragma unroll
      for (int i = 0; i < 3; ++i)
        af[i] = *(const short8*)(lds_w + (48 * cg + i * 16 + ml) * 72 + ks * 32 + qd * 8);
      #pragma unroll
      for (int j = 0; j < 4; ++j)
        bfr[j] = *(const short8*)(lds_v + (j * 16 + ml) * 72 + ks * 32 + qd * 8);
      #pragma unroll
      for (int i = 0; i < 3; ++i)
        #pragma unroll
        for (int j = 0; j < 4; ++j)
          acc[i][j] = __builtin_amdgcn_mfma_f32_16x16x32_bf16(af[i], bfr[j], acc[i][j], 0, 0, 0);
    }
  }

  __syncthreads();
  // --- spill h2h to LDS in [ch][px] (stride 65, conflict-free) ---
  #pragma unroll
  for (int i = 0; i < 3; ++i)
    #pragma unroll
    for (int j = 0; j < 4; ++j)
      #pragma unroll
      for (int r = 0; r < 4; ++r) {
        int ch = 48 * cg + i * 16 + qd * 4 + r;
        int px = j * 16 + ml;
        lds_h[ch * 65 + px] = acc[i][j][r];
      }
  __syncthreads();

  // --- gates: thread handles channels c = cg + 4k at pixel pp ---
  const float* i2hb = i2h + (size_t)b * 192 * HW + p;
  float* ob = outb + (size_t)b * ostr;
  #pragma unroll
  for (int k = 0; k < 16; ++k) {
    int c = cg + k * 4;
    float rh = lds_h[c * 65 + pp] + wb[c];
    float uh = lds_h[(64 + c) * 65 + pp] + wb[64 + c];
    float nh = lds_h[(128 + c) * 65 + pp] + wb[128 + c];
    float rt = i2hb[(size_t)c * HW];
    float ut = i2hb[(size_t)(64 + c) * HW];
    float nt = i2hb[(size_t)(128 + c) * HW];
    float r = sigmoidf_(rt + rh);
    float u = sigmoidf_(ut + uh);
    float n = sigmoidf_(nt + r * nh);
    float hp = hb[(size_t)c * HW + p];
    float hn = (1.0f - u) * n + u * hp;
    ob[(size_t)c * HW + p] = hn;
    if (lastb) lastb[((size_t)b * 64 + c) * HW + p] = hn;
  }
}

// ---------------------------------------------------------------------------
extern "C" void kernel_launch(void* const* d_in, const int* in_sizes, int n_in,
                              void* d_out, int out_size, void* d_ws, size_t ws_size,
                              hipStream_t stream)
{
  const float* inp   = (const float*)d_in[0];
  const float* state = (const float*)d_in[1];
  const float* i2h_w = (const float*)d_in[2];
  const float* i2h_b = (const float*)d_in[3];
  const float* i2f_w = (const float*)d_in[4];
  const float* i2f_b = (const float*)d_in[5];
  const float* h2f_w = (const float*)d_in[6];
  const float* h2f_b = (const float*)d_in[7];
  const float* fl_w  = (const float*)d_in[8];
  const float* fl_b  = (const float*)d_in[9];
  const float* wr_w  = (const float*)d_in[10];
  const float* wr_b  = (const float*)d_in[11];
  float* out = (float*)d_out;
  float* ws  = (float*)d_ws;

  // ws layout (floats): i2h 7077888 | f 1179648 | flows 958464 | wbf (shorts)
  float* ws_i2h = ws;
  float* ws_f   = ws + 7077888;
  float* ws_fl  = ws + 7077888 + 1179648;
  short* ws_wbf = (short*)(ws + 7077888 + 1179648 + 958464);

  const long long OB = (long long)10 * 64 * HW;

  k_wconv<<<dim3(624), 256, 0, stream>>>(wr_w, ws_wbf);

  for (int t = 0; t < 10; ++t) {
    const float* hbase = (t == 0) ? state : (out + (size_t)(t - 1) * 64 * HW);
    long long hstr = (t == 0) ? (long long)64 * HW : OB;

    k_i2h<<<dim3(36, 48, 4), 256, 0, stream>>>(inp, t, i2h_w, i2h_b, ws_i2h);
    k_f<<<dim3(24, 4, 4), 192, 0, stream>>>(inp, t, hbase, hstr,
                                            i2f_w, i2f_b, h2f_w, h2f_b, ws_f);
    k_flows<<<dim3(48, 2, 4), 192, 0, stream>>>(ws_f, fl_w, fl_b, ws_fl);

    float* outbase = out + (size_t)t * 64 * HW;
    float* lastb = (t == 9) ? (out + (size_t)4 * 10 * 64 * HW) : nullptr;
    k_fused<<<dim3(144, 4), 256, 0, stream>>>(ws_fl, hbase, hstr, ws_i2h,
                                              ws_wbf, wr_b, outbase, OB, lastb);
  }
}

// Round 3
// 6556.783 us; speedup vs baseline: 2.4703x; 1.6685x over previous
//
#include <hip/hip_runtime.h>
#include <math.h>

#define HW 9216   // 96*96

typedef __attribute__((ext_vector_type(8))) short short8;
typedef __attribute__((ext_vector_type(4))) float float4v;

__device__ __forceinline__ float sigmoidf_(float x) { return 1.0f / (1.0f + expf(-x)); }

__device__ __forceinline__ short bf16rne(float f) {
  unsigned u = __builtin_bit_cast(unsigned, f);
  unsigned r = (u + 0x7FFFu + ((u >> 16) & 1u)) >> 16;
  return (short)r;
}

// ---------------------------------------------------------------------------
// Kernel W: wrap_w (192,832) fp32 -> bf16 [l][n][c]
// ---------------------------------------------------------------------------
__global__ __launch_bounds__(256) void k_wconv(const float* __restrict__ w,
                                               short* __restrict__ o)
{
  int i = blockIdx.x * 256 + threadIdx.x;
  if (i >= 192 * 832) return;
  int n = i / 832, k = i % 832;
  int l = k >> 6, c = k & 63;
  o[((size_t)l * 192 + n) * 64 + c] = bf16rne(w[i]);
}

// ---------------------------------------------------------------------------
// Kernel A: i2h = conv3x3(x_t, 8->192, pad1) + bias
// blockIdx.z = t*4+b (batched, t_off=0) or z=b (per-step, t_off=t).
// out indexed by (blockIdx.z*192+o)*HW  -> [t][b][192][HW] when batched.
// ---------------------------------------------------------------------------
__global__ __launch_bounds__(256) void k_i2h(
    const float* __restrict__ inp, int t_off,
    const float* __restrict__ w, const float* __restrict__ bias,
    float* __restrict__ out)
{
  const int p  = blockIdx.x * 256 + threadIdx.x;
  const int og = blockIdx.y;                       // 0..47 -> o = og*4 + i
  const int zz = blockIdx.z;
  const int t  = zz >> 2, b = zz & 3;              // per-step: zz=b (t=0)
  const int y = p / 96, x = p % 96;
  const float* xin = inp + ((size_t)(b * 10 + t + t_off)) * 8 * HW;
  float acc[4];
  #pragma unroll
  for (int i = 0; i < 4; ++i) acc[i] = bias[og * 4 + i];
  for (int ci = 0; ci < 8; ++ci) {
    const float* xc = xin + (size_t)ci * HW;
    float v[9];
    #pragma unroll
    for (int ky = 0; ky < 3; ++ky) {
      int yy = y + ky - 1;
      bool vy = (yy >= 0) && (yy < 96);
      #pragma unroll
      for (int kx = 0; kx < 3; ++kx) {
        int xx = x + kx - 1;
        bool ok = vy && (xx >= 0) && (xx < 96);
        v[ky * 3 + kx] = ok ? xc[yy * 96 + xx] : 0.0f;
      }
    }
    #pragma unroll
    for (int i = 0; i < 4; ++i) {
      const float* wc = w + (((size_t)(og * 4 + i)) * 8 + ci) * 9;
      #pragma unroll
      for (int k = 0; k < 9; ++k) acc[i] += wc[k] * v[k];
    }
  }
  #pragma unroll
  for (int i = 0; i < 4; ++i)
    out[((size_t)(zz * 192 + og * 4 + i)) * HW + p] = acc[i];
}

// ---------------------------------------------------------------------------
// Kernel B: f = tanh(conv5x5(x_t,8->32) + conv5x5(h,64->32) + biases)
// grid (36, 8, 4), block 256. Tile 8 rows x 32 cols, 1 px/thread, 4 outs.
// Padded LDS tile (12x36, zero halo) -> inner loop has NO predication.
// ---------------------------------------------------------------------------
__global__ __launch_bounds__(256) void k_f(
    const float* __restrict__ inp, int t,
    const float* __restrict__ hbase, long long hstr,
    const float* __restrict__ wi, const float* __restrict__ bi,
    const float* __restrict__ wh, const float* __restrict__ bh,
    float* __restrict__ fout)
{
  __shared__ float tile[8 * 12 * 36];   // 13824 B
  const int tid = threadIdx.x;
  const int r0 = (blockIdx.x / 3) * 8;
  const int c0 = (blockIdx.x % 3) * 32;
  const int og = blockIdx.y;            // 0..7 -> outs og*4..og*4+3
  const int b  = blockIdx.z;
  const int r = tid >> 5, c = tid & 31;
  float acc[4];
  #pragma unroll
  for (int i = 0; i < 4; ++i) acc[i] = bi[og * 4 + i] + bh[og * 4 + i];
  const float* xin = inp + ((size_t)(b * 10 + t)) * 8 * HW;
  const float* hb  = hbase + (size_t)b * hstr;

  for (int cc = 0; cc < 9; ++cc) {      // 9 chunks of 8 channels
    __syncthreads();
    for (int i = tid; i < 8 * 432; i += 256) {
      int ci = i / 432, rem = i % 432;
      int rr = rem / 36, col = rem % 36;
      int grow = r0 + rr - 2, gcol = c0 + col - 2;
      int cig = cc * 8 + ci;
      const float* src = (cig < 8) ? (xin + (size_t)cig * HW)
                                   : (hb + (size_t)(cig - 8) * HW);
      bool ok = (grow >= 0) && (grow < 96) && (gcol >= 0) && (gcol < 96);
      tile[i] = ok ? src[grow * 96 + gcol] : 0.0f;
    }
    __syncthreads();
    for (int ci = 0; ci < 8; ++ci) {
      int cig = cc * 8 + ci;
      const float* wbase = (cig < 8) ? (wi + (((size_t)(og * 4)) * 8 + cig) * 25)
                                     : (wh + (((size_t)(og * 4)) * 64 + (cig - 8)) * 25);
      const int wstride = (cig < 8) ? 8 * 25 : 64 * 25;
      const float* tb = &tile[ci * 432 + r * 36 + c];
      #pragma unroll
      for (int ky = 0; ky < 5; ++ky) {
        #pragma unroll
        for (int kx = 0; kx < 5; ++kx) {
          float v = tb[ky * 36 + kx];
          #pragma unroll
          for (int i = 0; i < 4; ++i)
            acc[i] += wbase[(size_t)i * wstride + ky * 5 + kx] * v;
        }
      }
    }
  }
  float* fo = fout + (size_t)b * 32 * HW + (size_t)(r0 + r) * 96 + (c0 + c);
  #pragma unroll
  for (int i = 0; i < 4; ++i)
    fo[(size_t)(og * 4 + i) * HW] = tanhf(acc[i]);
}

// ---------------------------------------------------------------------------
// Kernel C: flows partials. K split in 4 chunks of 8 ci across blockIdx.x.
// grid (144, 2, 4): blockIdx.x = tile*4 + kc. block 256, tile 8x32.
// partial kc -> flp + kc*FL ; bias folded into kc==0.
// ---------------------------------------------------------------------------
__global__ __launch_bounds__(256) void k_flows(
    const float* __restrict__ f,
    const float* __restrict__ w, const float* __restrict__ bias,
    float* __restrict__ flp, long long FL)
{
  __shared__ float tile[8 * 12 * 36];
  const int tid = threadIdx.x;
  const int bx = blockIdx.x;
  const int kc = bx & 3, tl = bx >> 2;
  const int r0 = (tl / 3) * 8;
  const int c0 = (tl % 3) * 32;
  const int og = blockIdx.y;            // 0..1 -> 13 outs
  const int b  = blockIdx.z;
  const int r = tid >> 5, c = tid & 31;
  float acc[13];
  #pragma unroll
  for (int i = 0; i < 13; ++i) acc[i] = (kc == 0) ? bias[og * 13 + i] : 0.0f;
  const float* fb = f + (size_t)b * 32 * HW + (size_t)(kc * 8) * HW;

  __syncthreads();
  for (int i = tid; i < 8 * 432; i += 256) {
    int ci = i / 432, rem = i % 432;
    int rr = rem / 36, col = rem % 36;
    int grow = r0 + rr - 2, gcol = c0 + col - 2;
    bool ok = (grow >= 0) && (grow < 96) && (gcol >= 0) && (gcol < 96);
    tile[i] = ok ? fb[(size_t)ci * HW + grow * 96 + gcol] : 0.0f;
  }
  __syncthreads();
  for (int ci = 0; ci < 8; ++ci) {
    int cig = kc * 8 + ci;
    const float* tb = &tile[ci * 432 + r * 36 + c];
    #pragma unroll
    for (int ky = 0; ky < 5; ++ky) {
      #pragma unroll
      for (int kx = 0; kx < 5; ++kx) {
        float v = tb[ky * 36 + kx];
        #pragma unroll
        for (int i = 0; i < 13; ++i)
          acc[i] += w[(((size_t)(og * 13 + i)) * 32 + cig) * 25 + ky * 5 + kx] * v;
      }
    }
  }
  float* fo = flp + (size_t)kc * FL + (size_t)b * 26 * HW
            + (size_t)(r0 + r) * 96 + (c0 + c);
  #pragma unroll
  for (int i = 0; i < 13; ++i)
    fo[(size_t)(og * 13 + i) * HW] = acc[i];
}

__device__ __forceinline__ float bilin_(const float* __restrict__ hc,
                                        int o00, int o01, int o10, int o11,
                                        float w00, float w01, float w10, float w11)
{
  float s = 0.0f;
  if (o00 >= 0) s += w00 * hc[o00];
  if (o01 >= 0) s += w01 * hc[o01];
  if (o10 >= 0) s += w10 * hc[o10];
  if (o11 >= 0) s += w11 * hc[o11];
  return s;
}

// ---------------------------------------------------------------------------
// Kernel D: fused warp + 1x1 conv (bf16 MFMA) + gates. grid (144,4), block 256.
// flows read as sum of 4 K-split partials.
// ---------------------------------------------------------------------------
__global__ __launch_bounds__(256) void k_fused(
    const float* __restrict__ flp, long long FL,  // partials (4x)
    const float* __restrict__ hbase, long long hstr,
    const float* __restrict__ i2h,                // this step's (B,192,HW)
    const short* __restrict__ wbf,                // bf16 [13][192][64]
    const float* __restrict__ wb,
    float* __restrict__ outb, long long ostr,
    float* __restrict__ lastb)
{
  __shared__ __align__(16) char smem_raw[49920];
  short* lds_w = (short*)smem_raw;
  short* lds_v = lds_w + 192 * 72;
  float* lds_h = (float*)smem_raw;

  const int tid = threadIdx.x;
  const int pp  = tid & 63;
  const int cg  = tid >> 6;
  const int b   = blockIdx.y;
  const int p   = blockIdx.x * 64 + pp;
  const int ypix = p / 96, xpix = p % 96;
  const float* hb  = hbase + (size_t)b * hstr;
  const float* flb = flp + (size_t)b * 26 * HW;
  const int ml = pp & 15;
  const int qd = pp >> 4;

  float4v acc[3][4];
  #pragma unroll
  for (int i = 0; i < 3; ++i)
    #pragma unroll
    for (int j = 0; j < 4; ++j)
      #pragma unroll
      for (int r = 0; r < 4; ++r) acc[i][j][r] = 0.0f;

  for (int l = 0; l < 13; ++l) {
    __syncthreads();
    {
      const short* wsrc = wbf + (size_t)l * 192 * 64;
      #pragma unroll
      for (int it = 0; it < 6; ++it) {
        int idx = tid + it * 256;
        int n = idx >> 3, c8 = (idx & 7) * 8;
        short8 v = *(const short8*)(wsrc + n * 64 + c8);
        *(short8*)(lds_w + n * 72 + c8) = v;
      }
    }
    float fx = flb[(size_t)(2 * l) * HW + p]         + flb[FL + (size_t)(2 * l) * HW + p]
             + flb[2 * FL + (size_t)(2 * l) * HW + p] + flb[3 * FL + (size_t)(2 * l) * HW + p];
    float fy = flb[(size_t)(2 * l + 1) * HW + p]         + flb[FL + (size_t)(2 * l + 1) * HW + p]
             + flb[2 * FL + (size_t)(2 * l + 1) * HW + p] + flb[3 * FL + (size_t)(2 * l + 1) * HW + p];
    float vx = (float)xpix - fx;
    float vy = (float)ypix - fy;
    float gxn = 2.0f * vx / 96.0f - 1.0f;
    float gyn = 2.0f * vy / 96.0f - 1.0f;
    float ix = ((gxn + 1.0f) * 96.0f - 1.0f) * 0.5f;
    float iy = ((gyn + 1.0f) * 96.0f - 1.0f) * 0.5f;
    float x0f = floorf(ix), y0f = floorf(iy);
    float wx1 = ix - x0f, wy1 = iy - y0f;
    float wx0 = 1.0f - wx1, wy0 = 1.0f - wy1;
    int x0 = (int)x0f, y0 = (int)y0f;
    bool vx0 = (x0 >= 0) && (x0 < 96);
    bool vx1 = (x0 + 1 >= 0) && (x0 + 1 < 96);
    bool vy0g = (y0 >= 0) && (y0 < 96);
    bool vy1g = (y0 + 1 >= 0) && (y0 + 1 < 96);
    int o00 = (vx0 && vy0g) ? (y0 * 96 + x0)           : -1;
    int o01 = (vx1 && vy0g) ? (y0 * 96 + x0 + 1)       : -1;
    int o10 = (vx0 && vy1g) ? ((y0 + 1) * 96 + x0)     : -1;
    int o11 = (vx1 && vy1g) ? ((y0 + 1) * 96 + x0 + 1) : -1;
    float w00 = wy0 * wx0, w01 = wy0 * wx1, w10 = wy1 * wx0, w11 = wy1 * wx1;

    short vv[16];
    #pragma unroll
    for (int k = 0; k < 16; ++k) {
      int cch = cg * 16 + k;
      float s = bilin_(hb + (size_t)cch * HW, o00, o01, o10, o11, w00, w01, w10, w11);
      vv[k] = bf16rne(s);
    }
    *(short8*)(lds_v + pp * 72 + cg * 16)     = *(short8*)&vv[0];
    *(short8*)(lds_v + pp * 72 + cg * 16 + 8) = *(short8*)&vv[8];
    __syncthreads();

    #pragma unroll
    for (int ks = 0; ks < 2; ++ks) {
      short8 af[3], bfr[4];
      #pragma unroll
      for (int i = 0; i < 3; ++i)
        af[i] = *(const short8*)(lds_w + (48 * cg + i * 16 + ml) * 72 + ks * 32 + qd * 8);
      #pragma unroll
      for (int j = 0; j < 4; ++j)
        bfr[j] = *(const short8*)(lds_v + (j * 16 + ml) * 72 + ks * 32 + qd * 8);
      #pragma unroll
      for (int i = 0; i < 3; ++i)
        #pragma unroll
        for (int j = 0; j < 4; ++j)
          acc[i][j] = __builtin_amdgcn_mfma_f32_16x16x32_bf16(af[i], bfr[j], acc[i][j], 0, 0, 0);
    }
  }

  __syncthreads();
  #pragma unroll
  for (int i = 0; i < 3; ++i)
    #pragma unroll
    for (int j = 0; j < 4; ++j)
      #pragma unroll
      for (int r = 0; r < 4; ++r) {
        int ch = 48 * cg + i * 16 + qd * 4 + r;
        int px = j * 16 + ml;
        lds_h[ch * 65 + px] = acc[i][j][r];
      }
  __syncthreads();

  const float* i2hb = i2h + (size_t)b * 192 * HW + p;
  float* ob = outb + (size_t)b * ostr;
  #pragma unroll
  for (int k = 0; k < 16; ++k) {
    int cch = cg + k * 4;
    float rh = lds_h[cch * 65 + pp] + wb[cch];
    float uh = lds_h[(64 + cch) * 65 + pp] + wb[64 + cch];
    float nh = lds_h[(128 + cch) * 65 + pp] + wb[128 + cch];
    float rt = i2hb[(size_t)cch * HW];
    float ut = i2hb[(size_t)(64 + cch) * HW];
    float nt = i2hb[(size_t)(128 + cch) * HW];
    float rr = sigmoidf_(rt + rh);
    float uu = sigmoidf_(ut + uh);
    float nn = sigmoidf_(nt + rr * nh);
    float hp = hb[(size_t)cch * HW + p];
    float hn = (1.0f - uu) * nn + uu * hp;
    ob[(size_t)cch * HW + p] = hn;
    if (lastb) lastb[((size_t)b * 64 + cch) * HW + p] = hn;
  }
}

// ---------------------------------------------------------------------------
extern "C" void kernel_launch(void* const* d_in, const int* in_sizes, int n_in,
                              void* d_out, int out_size, void* d_ws, size_t ws_size,
                              hipStream_t stream)
{
  const float* inp   = (const float*)d_in[0];
  const float* state = (const float*)d_in[1];
  const float* i2h_w = (const float*)d_in[2];
  const float* i2h_b = (const float*)d_in[3];
  const float* i2f_w = (const float*)d_in[4];
  const float* i2f_b = (const float*)d_in[5];
  const float* h2f_w = (const float*)d_in[6];
  const float* h2f_b = (const float*)d_in[7];
  const float* fl_w  = (const float*)d_in[8];
  const float* fl_b  = (const float*)d_in[9];
  const float* wr_w  = (const float*)d_in[10];
  const float* wr_b  = (const float*)d_in[11];
  float* out = (float*)d_out;
  float* ws  = (float*)d_ws;

  const long long F_I2H = 7077888;    // 4*192*HW
  const long long F_F   = 1179648;    // 4*32*HW
  const long long F_FL  = 958464;     // 4*26*HW
  const long long OB    = (long long)10 * 64 * HW;

  // batched i2h path needs 10*F_I2H; otherwise 1*F_I2H
  bool batched = ws_size >= (size_t)(10 * F_I2H + F_F + 4 * F_FL + 79872) * 4ULL;
  long long i2h_fl = batched ? 10 * F_I2H : F_I2H;

  float* ws_i2h = ws;
  float* ws_f   = ws + i2h_fl;
  float* ws_fl  = ws_f + F_F;
  short* ws_wbf = (short*)(ws_fl + 4 * F_FL);

  k_wconv<<<dim3(624), 256, 0, stream>>>(wr_w, ws_wbf);
  if (batched)
    k_i2h<<<dim3(36, 48, 40), 256, 0, stream>>>(inp, 0, i2h_w, i2h_b, ws_i2h);

  for (int t = 0; t < 10; ++t) {
    const float* hbase = (t == 0) ? state : (out + (size_t)(t - 1) * 64 * HW);
    long long hstr = (t == 0) ? (long long)64 * HW : OB;

    if (!batched)
      k_i2h<<<dim3(36, 48, 4), 256, 0, stream>>>(inp, t, i2h_w, i2h_b, ws_i2h);
    k_f<<<dim3(36, 8, 4), 256, 0, stream>>>(inp, t, hbase, hstr,
                                            i2f_w, i2f_b, h2f_w, h2f_b, ws_f);
    k_flows<<<dim3(144, 2, 4), 256, 0, stream>>>(ws_f, fl_w, fl_b, ws_fl, F_FL);

    const float* i2h_t = batched ? (ws_i2h + (size_t)t * F_I2H) : ws_i2h;
    float* outbase = out + (size_t)t * 64 * HW;
    float* lastb = (t == 9) ? (out + (size_t)4 * 10 * 64 * HW) : nullptr;
    k_fused<<<dim3(144, 4), 256, 0, stream>>>(ws_fl, F_FL, hbase, hstr, i2h_t,
                                              ws_wbf, wr_b, outbase, OB, lastb);
  }
}

// Round 4
// 3305.918 us; speedup vs baseline: 4.8996x; 1.9833x over previous
//
#include <hip/hip_runtime.h>
#include <math.h>

#define HW 9216   // 96*96

typedef __attribute__((ext_vector_type(8))) short short8;
typedef __attribute__((ext_vector_type(4))) float float4v;

__device__ __forceinline__ float sigmoidf_(float x) { return 1.0f / (1.0f + expf(-x)); }

__device__ __forceinline__ short bf16rne(float f) {
  unsigned u = __builtin_bit_cast(unsigned, f);
  unsigned r = (u + 0x7FFFu + ((u >> 16) & 1u)) >> 16;
  return (short)r;
}
__device__ __forceinline__ float bf2f(short s) {
  return __builtin_bit_cast(float, ((unsigned)(unsigned short)s) << 16);
}

// ---------------------------------------------------------------------------
// Kernel W: wrap_w (192,832) fp32 -> bf16 [l][n][c]
// ---------------------------------------------------------------------------
__global__ __launch_bounds__(256) void k_wconv(const float* __restrict__ w,
                                               short* __restrict__ o)
{
  int i = blockIdx.x * 256 + threadIdx.x;
  if (i >= 192 * 832) return;
  int n = i / 832, k = i % 832;
  int l = k >> 6, c = k & 63;
  o[((size_t)l * 192 + n) * 64 + c] = bf16rne(w[i]);
}

// ---------------------------------------------------------------------------
// Kernel H: state (4,64,HW) fp32 NCHW -> hbf [b][px][64] bf16 (t=0 seed)
// ---------------------------------------------------------------------------
__global__ __launch_bounds__(256) void k_h2bf(const float* __restrict__ st,
                                              short* __restrict__ hbf)
{
  const int tid = threadIdx.x;
  const int pp = tid & 63, cg = tid >> 6;
  const int b = blockIdx.y;
  const int p = blockIdx.x * 64 + pp;
  short s[16];
  #pragma unroll
  for (int k = 0; k < 16; ++k)
    s[k] = bf16rne(st[((size_t)b * 64 + cg * 16 + k) * HW + p]);
  short* dst = hbf + ((size_t)b * HW + p) * 64 + cg * 16;
  *(short8*)dst = *(short8*)&s[0];
  *(short8*)(dst + 8) = *(short8*)&s[8];
}

// ---------------------------------------------------------------------------
// Kernel A: i2h = conv3x3(x_t, 8->192, pad1) + bias
// blockIdx.z = t*4+b (batched, t_off=0) or z=b (per-step, t_off=t).
// ---------------------------------------------------------------------------
__global__ __launch_bounds__(256) void k_i2h(
    const float* __restrict__ inp, int t_off,
    const float* __restrict__ w, const float* __restrict__ bias,
    float* __restrict__ out)
{
  const int p  = blockIdx.x * 256 + threadIdx.x;
  const int og = blockIdx.y;
  const int zz = blockIdx.z;
  const int t  = zz >> 2, b = zz & 3;
  const int y = p / 96, x = p % 96;
  const float* xin = inp + ((size_t)(b * 10 + t + t_off)) * 8 * HW;
  float acc[4];
  #pragma unroll
  for (int i = 0; i < 4; ++i) acc[i] = bias[og * 4 + i];
  for (int ci = 0; ci < 8; ++ci) {
    const float* xc = xin + (size_t)ci * HW;
    float v[9];
    #pragma unroll
    for (int ky = 0; ky < 3; ++ky) {
      int yy = y + ky - 1;
      bool vy = (yy >= 0) && (yy < 96);
      #pragma unroll
      for (int kx = 0; kx < 3; ++kx) {
        int xx = x + kx - 1;
        bool ok = vy && (xx >= 0) && (xx < 96);
        v[ky * 3 + kx] = ok ? xc[yy * 96 + xx] : 0.0f;
      }
    }
    #pragma unroll
    for (int i = 0; i < 4; ++i) {
      const float* wc = w + (((size_t)(og * 4 + i)) * 8 + ci) * 9;
      #pragma unroll
      for (int k = 0; k < 9; ++k) acc[i] += wc[k] * v[k];
    }
  }
  #pragma unroll
  for (int i = 0; i < 4; ++i)
    out[((size_t)(zz * 192 + og * 4 + i)) * HW + p] = acc[i];
}

// ---------------------------------------------------------------------------
// Kernel B: f = tanh(conv5x5(x_t,8->32) + conv5x5(h,64->32) + biases)
// grid (36, 8, 4), block 256. Tile 8x32, padded LDS, no inner predication.
// ---------------------------------------------------------------------------
__global__ __launch_bounds__(256) void k_f(
    const float* __restrict__ inp, int t,
    const float* __restrict__ hbase, long long hstr,
    const float* __restrict__ wi, const float* __restrict__ bi,
    const float* __restrict__ wh, const float* __restrict__ bh,
    float* __restrict__ fout)
{
  __shared__ float tile[8 * 12 * 36];
  const int tid = threadIdx.x;
  const int r0 = (blockIdx.x / 3) * 8;
  const int c0 = (blockIdx.x % 3) * 32;
  const int og = blockIdx.y;
  const int b  = blockIdx.z;
  const int r = tid >> 5, c = tid & 31;
  float acc[4];
  #pragma unroll
  for (int i = 0; i < 4; ++i) acc[i] = bi[og * 4 + i] + bh[og * 4 + i];
  const float* xin = inp + ((size_t)(b * 10 + t)) * 8 * HW;
  const float* hb  = hbase + (size_t)b * hstr;

  for (int cc = 0; cc < 9; ++cc) {
    __syncthreads();
    for (int i = tid; i < 8 * 432; i += 256) {
      int ci = i / 432, rem = i % 432;
      int rr = rem / 36, col = rem % 36;
      int grow = r0 + rr - 2, gcol = c0 + col - 2;
      int cig = cc * 8 + ci;
      const float* src = (cig < 8) ? (xin + (size_t)cig * HW)
                                   : (hb + (size_t)(cig - 8) * HW);
      bool ok = (grow >= 0) && (grow < 96) && (gcol >= 0) && (gcol < 96);
      tile[i] = ok ? src[grow * 96 + gcol] : 0.0f;
    }
    __syncthreads();
    for (int ci = 0; ci < 8; ++ci) {
      int cig = cc * 8 + ci;
      const float* wbase = (cig < 8) ? (wi + (((size_t)(og * 4)) * 8 + cig) * 25)
                                     : (wh + (((size_t)(og * 4)) * 64 + (cig - 8)) * 25);
      const int wstride = (cig < 8) ? 8 * 25 : 64 * 25;
      const float* tb = &tile[ci * 432 + r * 36 + c];
      #pragma unroll
      for (int ky = 0; ky < 5; ++ky) {
        #pragma unroll
        for (int kx = 0; kx < 5; ++kx) {
          float v = tb[ky * 36 + kx];
          #pragma unroll
          for (int i = 0; i < 4; ++i)
            acc[i] += wbase[(size_t)i * wstride + ky * 5 + kx] * v;
        }
      }
    }
  }
  float* fo = fout + (size_t)b * 32 * HW + (size_t)(r0 + r) * 96 + (c0 + c);
  #pragma unroll
  for (int i = 0; i < 4; ++i)
    fo[(size_t)(og * 4 + i) * HW] = tanhf(acc[i]);
}

// ---------------------------------------------------------------------------
// Kernel C: flows partials. K split in 4 chunks across blockIdx.x.
// ---------------------------------------------------------------------------
__global__ __launch_bounds__(256) void k_flows(
    const float* __restrict__ f,
    const float* __restrict__ w, const float* __restrict__ bias,
    float* __restrict__ flp, long long FL)
{
  __shared__ float tile[8 * 12 * 36];
  const int tid = threadIdx.x;
  const int bx = blockIdx.x;
  const int kc = bx & 3, tl = bx >> 2;
  const int r0 = (tl / 3) * 8;
  const int c0 = (tl % 3) * 32;
  const int og = blockIdx.y;
  const int b  = blockIdx.z;
  const int r = tid >> 5, c = tid & 31;
  float acc[13];
  #pragma unroll
  for (int i = 0; i < 13; ++i) acc[i] = (kc == 0) ? bias[og * 13 + i] : 0.0f;
  const float* fb = f + (size_t)b * 32 * HW + (size_t)(kc * 8) * HW;

  __syncthreads();
  for (int i = tid; i < 8 * 432; i += 256) {
    int ci = i / 432, rem = i % 432;
    int rr = rem / 36, col = rem % 36;
    int grow = r0 + rr - 2, gcol = c0 + col - 2;
    bool ok = (grow >= 0) && (grow < 96) && (gcol >= 0) && (gcol < 96);
    tile[i] = ok ? fb[(size_t)ci * HW + grow * 96 + gcol] : 0.0f;
  }
  __syncthreads();
  for (int ci = 0; ci < 8; ++ci) {
    int cig = kc * 8 + ci;
    const float* tb = &tile[ci * 432 + r * 36 + c];
    #pragma unroll
    for (int ky = 0; ky < 5; ++ky) {
      #pragma unroll
      for (int kx = 0; kx < 5; ++kx) {
        float v = tb[ky * 36 + kx];
        #pragma unroll
        for (int i = 0; i < 13; ++i)
          acc[i] += w[(((size_t)(og * 13 + i)) * 32 + cig) * 25 + ky * 5 + kx] * v;
      }
    }
  }
  float* fo = flp + (size_t)kc * FL + (size_t)b * 26 * HW
            + (size_t)(r0 + r) * 96 + (c0 + c);
  #pragma unroll
  for (int i = 0; i < 13; ++i)
    fo[(size_t)(og * 13 + i) * HW] = acc[i];
}

// ---------------------------------------------------------------------------
// Kernel S: sum 4 flow partials -> single buffer (float4)
// ---------------------------------------------------------------------------
__global__ __launch_bounds__(256) void k_flsum(const float* __restrict__ flp,
                                               long long FL,
                                               float* __restrict__ fls)
{
  long long i = (long long)blockIdx.x * 256 + threadIdx.x;   // float4 index
  const float4v* a = (const float4v*)flp;
  long long FL4 = FL >> 2;
  float4v v = a[i];
  float4v v1 = a[i + FL4], v2 = a[i + 2 * FL4], v3 = a[i + 3 * FL4];
  #pragma unroll
  for (int k = 0; k < 4; ++k) v[k] = v[k] + v1[k] + v2[k] + v3[k];
  ((float4v*)fls)[i] = v;
}

// ---------------------------------------------------------------------------
// Kernel D: fused warp (channel-last bf16 h) + 1x1 conv (bf16 MFMA) + gates.
// 1-D grid 576 blocks, XCD-batch affinity swizzle: xcd pair {2b,2b+1} <-> batch b
// so each XCD's L2 only holds one batch's 1.18 MB hbf slice.
// ---------------------------------------------------------------------------
__global__ __launch_bounds__(256) void k_fused(
    const float* __restrict__ fls,                // summed flows (B,26,HW)
    const float* __restrict__ hbase, long long hstr,  // prev h fp32 NCHW (exact)
    const short* __restrict__ hbf_in,             // prev h bf16 [b][px][64]
    const float* __restrict__ i2h,                // this step's (B,192,HW)
    const short* __restrict__ wbf,                // bf16 [13][192][64]
    const float* __restrict__ wb,
    float* __restrict__ outb, long long ostr,
    short* __restrict__ hbf_out,                  // next h bf16 [b][px][64]
    float* __restrict__ lastb)
{
  __shared__ __align__(16) char smem_raw[49920];
  short* lds_w = (short*)smem_raw;
  short* lds_v = lds_w + 192 * 72;
  float* lds_h = (float*)smem_raw;
  short* hpack = (short*)smem_raw;    // 64 x 80 shorts (after final sync)

  const int tid = threadIdx.x;
  const int pp  = tid & 63;
  const int cg  = tid >> 6;
  // XCD-batch affinity swizzle (perf heuristic only)
  const int ii  = blockIdx.x;
  const int xcd = ii & 7;
  const int b   = xcd >> 1;
  const int tile = ((ii >> 3) << 1) | (xcd & 1);   // 0..143
  const int p   = tile * 64 + pp;
  const int ypix = p / 96, xpix = p % 96;
  const float* hb  = hbase + (size_t)b * hstr;
  const short* hvp = hbf_in + ((size_t)b * HW) * 64 + cg * 16;
  const float* flb = fls + (size_t)b * 26 * HW;
  const int ml = pp & 15;
  const int qd = pp >> 4;

  float4v acc[3][4];
  #pragma unroll
  for (int i = 0; i < 3; ++i)
    #pragma unroll
    for (int j = 0; j < 4; ++j)
      #pragma unroll
      for (int r = 0; r < 4; ++r) acc[i][j][r] = 0.0f;

  for (int l = 0; l < 13; ++l) {
    __syncthreads();
    {
      const short* wsrc = wbf + (size_t)l * 192 * 64;
      #pragma unroll
      for (int it = 0; it < 6; ++it) {
        int idx = tid + it * 256;
        int n = idx >> 3, c8 = (idx & 7) * 8;
        short8 v = *(const short8*)(wsrc + n * 64 + c8);
        *(short8*)(lds_w + n * 72 + c8) = v;
      }
    }
    float fx = flb[(size_t)(2 * l) * HW + p];
    float fy = flb[(size_t)(2 * l + 1) * HW + p];
    float vx = (float)xpix - fx;
    float vy = (float)ypix - fy;
    float gxn = 2.0f * vx / 96.0f - 1.0f;
    float gyn = 2.0f * vy / 96.0f - 1.0f;
    float ix = ((gxn + 1.0f) * 96.0f - 1.0f) * 0.5f;
    float iy = ((gyn + 1.0f) * 96.0f - 1.0f) * 0.5f;
    float x0f = floorf(ix), y0f = floorf(iy);
    float wx1 = ix - x0f, wy1 = iy - y0f;
    float wx0 = 1.0f - wx1, wy0 = 1.0f - wy1;
    int x0 = (int)x0f, y0 = (int)y0f;
    bool vx0 = (x0 >= 0) && (x0 < 96);
    bool vx1 = (x0 + 1 >= 0) && (x0 + 1 < 96);
    bool vy0g = (y0 >= 0) && (y0 < 96);
    bool vy1g = (y0 + 1 >= 0) && (y0 + 1 < 96);
    int o00 = (vx0 && vy0g) ? (y0 * 96 + x0)           : -1;
    int o01 = (vx1 && vy0g) ? (y0 * 96 + x0 + 1)       : -1;
    int o10 = (vx0 && vy1g) ? ((y0 + 1) * 96 + x0)     : -1;
    int o11 = (vx1 && vy1g) ? ((y0 + 1) * 96 + x0 + 1) : -1;
    float w00 = wy0 * wx0, w01 = wy0 * wx1, w10 = wy1 * wx0, w11 = wy1 * wx1;

    // gather 16 channels (cg*16..+15), 4 taps of 32B contiguous bf16
    float sum[16];
    #pragma unroll
    for (int k = 0; k < 16; ++k) sum[k] = 0.0f;
    #define TAP_(off, wgt)                                            \
      if ((off) >= 0) {                                               \
        const short* tp = hvp + (size_t)(off) * 64;                   \
        short8 u0 = *(const short8*)tp;                               \
        short8 u1 = *(const short8*)(tp + 8);                         \
        _Pragma("unroll")                                             \
        for (int k = 0; k < 8; ++k) {                                 \
          sum[k]     += (wgt) * bf2f(u0[k]);                          \
          sum[k + 8] += (wgt) * bf2f(u1[k]);                          \
        }                                                             \
      }
    TAP_(o00, w00) TAP_(o01, w01) TAP_(o10, w10) TAP_(o11, w11)
    #undef TAP_
    short vv[16];
    #pragma unroll
    for (int k = 0; k < 16; ++k) vv[k] = bf16rne(sum[k]);
    *(short8*)(lds_v + pp * 72 + cg * 16)     = *(short8*)&vv[0];
    *(short8*)(lds_v + pp * 72 + cg * 16 + 8) = *(short8*)&vv[8];
    __syncthreads();

    #pragma unroll
    for (int ks = 0; ks < 2; ++ks) {
      short8 af[3], bfr[4];
      #pragma unroll
      for (int i = 0; i < 3; ++i)
        af[i] = *(const short8*)(lds_w + (48 * cg + i * 16 + ml) * 72 + ks * 32 + qd * 8);
      #pragma unroll
      for (int j = 0; j < 4; ++j)
        bfr[j] = *(const short8*)(lds_v + (j * 16 + ml) * 72 + ks * 32 + qd * 8);
      #pragma unroll
      for (int i = 0; i < 3; ++i)
        #pragma unroll
        for (int j = 0; j < 4; ++j)
          acc[i][j] = __builtin_amdgcn_mfma_f32_16x16x32_bf16(af[i], bfr[j], acc[i][j], 0, 0, 0);
    }
  }

  __syncthreads();
  #pragma unroll
  for (int i = 0; i < 3; ++i)
    #pragma unroll
    for (int j = 0; j < 4; ++j)
      #pragma unroll
      for (int r = 0; r < 4; ++r) {
        int ch = 48 * cg + i * 16 + qd * 4 + r;
        int px = j * 16 + ml;
        lds_h[ch * 65 + px] = acc[i][j][r];
      }
  __syncthreads();

  const float* i2hb = i2h + (size_t)b * 192 * HW + p;
  float* ob = outb + (size_t)b * ostr;
  float hnv[16];
  #pragma unroll
  for (int k = 0; k < 16; ++k) {
    int cch = cg + k * 4;
    float rh = lds_h[cch * 65 + pp] + wb[cch];
    float uh = lds_h[(64 + cch) * 65 + pp] + wb[64 + cch];
    float nh = lds_h[(128 + cch) * 65 + pp] + wb[128 + cch];
    float rt = i2hb[(size_t)cch * HW];
    float ut = i2hb[(size_t)(64 + cch) * HW];
    float nt = i2hb[(size_t)(128 + cch) * HW];
    float rr = sigmoidf_(rt + rh);
    float uu = sigmoidf_(ut + uh);
    float nn = sigmoidf_(nt + rr * nh);
    float hp = hb[(size_t)cch * HW + p];
    float hn = (1.0f - uu) * nn + uu * hp;
    ob[(size_t)cch * HW + p] = hn;
    if (lastb) lastb[((size_t)b * 64 + cch) * HW + p] = hn;
    hnv[k] = hn;
  }

  // transpose hn -> channel-last bf16 via LDS, coalesced 32B stores
  __syncthreads();
  #pragma unroll
  for (int k = 0; k < 16; ++k)
    hpack[pp * 80 + cg + 4 * k] = bf16rne(hnv[k]);
  __syncthreads();
  {
    int px = tid >> 2, g = tid & 3;
    short8 a0 = *(short8*)(hpack + px * 80 + g * 16);
    short8 a1 = *(short8*)(hpack + px * 80 + g * 16 + 8);
    short* dst = hbf_out + ((size_t)b * HW + tile * 64 + px) * 64 + g * 16;
    *(short8*)dst = a0;
    *(short8*)(dst + 8) = a1;
  }
}

// ---------------------------------------------------------------------------
extern "C" void kernel_launch(void* const* d_in, const int* in_sizes, int n_in,
                              void* d_out, int out_size, void* d_ws, size_t ws_size,
                              hipStream_t stream)
{
  const float* inp   = (const float*)d_in[0];
  const float* state = (const float*)d_in[1];
  const float* i2h_w = (const float*)d_in[2];
  const float* i2h_b = (const float*)d_in[3];
  const float* i2f_w = (const float*)d_in[4];
  const float* i2f_b = (const float*)d_in[5];
  const float* h2f_w = (const float*)d_in[6];
  const float* h2f_b = (const float*)d_in[7];
  const float* fl_w  = (const float*)d_in[8];
  const float* fl_b  = (const float*)d_in[9];
  const float* wr_w  = (const float*)d_in[10];
  const float* wr_b  = (const float*)d_in[11];
  float* out = (float*)d_out;
  float* ws  = (float*)d_ws;

  const long long F_I2H = 7077888;    // 4*192*HW floats
  const long long F_F   = 1179648;    // 4*32*HW
  const long long F_FL  = 958464;     // 4*26*HW
  const long long F_HB  = 1179648;    // 4*HW*64 shorts / 2 (in floats)
  const long long OB    = (long long)10 * 64 * HW;

  const long long fixed = F_F + 4 * F_FL + F_FL + 2 * F_HB + 79872;
  bool batched = ws_size >= (size_t)(10 * F_I2H + fixed) * 4ULL;
  long long i2h_fl = batched ? 10 * F_I2H : F_I2H;

  float* ws_i2h = ws;
  float* ws_f   = ws_i2h + i2h_fl;
  float* ws_flp = ws_f + F_F;
  float* ws_fls = ws_flp + 4 * F_FL;
  short* hbfA   = (short*)(ws_fls + F_FL);
  short* hbfB   = (short*)(ws_fls + F_FL + F_HB);
  short* ws_wbf = (short*)(ws_fls + F_FL + 2 * F_HB);

  k_wconv<<<dim3(624), 256, 0, stream>>>(wr_w, ws_wbf);
  k_h2bf<<<dim3(144, 4), 256, 0, stream>>>(state, hbfA);
  if (batched)
    k_i2h<<<dim3(36, 48, 40), 256, 0, stream>>>(inp, 0, i2h_w, i2h_b, ws_i2h);

  for (int t = 0; t < 10; ++t) {
    const float* hbase = (t == 0) ? state : (out + (size_t)(t - 1) * 64 * HW);
    long long hstr = (t == 0) ? (long long)64 * HW : OB;
    short* hin  = (t & 1) ? hbfB : hbfA;
    short* hout = (t & 1) ? hbfA : hbfB;

    if (!batched)
      k_i2h<<<dim3(36, 48, 4), 256, 0, stream>>>(inp, t, i2h_w, i2h_b, ws_i2h);
    k_f<<<dim3(36, 8, 4), 256, 0, stream>>>(inp, t, hbase, hstr,
                                            i2f_w, i2f_b, h2f_w, h2f_b, ws_f);
    k_flows<<<dim3(144, 2, 4), 256, 0, stream>>>(ws_f, fl_w, fl_b, ws_flp, F_FL);
    k_flsum<<<dim3(936), 256, 0, stream>>>(ws_flp, F_FL, ws_fls);

    const float* i2h_t = batched ? (ws_i2h + (size_t)t * F_I2H) : ws_i2h;
    float* outbase = out + (size_t)t * 64 * HW;
    float* lastb = (t == 9) ? (out + (size_t)4 * 10 * 64 * HW) : nullptr;
    k_fused<<<dim3(576), 256, 0, stream>>>(ws_fls, hbase, hstr, hin, i2h_t,
                                           ws_wbf, wr_b, outbase, OB, hout, lastb);
  }
}

// Round 5
// 1689.747 us; speedup vs baseline: 9.5858x; 1.9565x over previous
//
#include <hip/hip_runtime.h>
#include <math.h>

#define HW 9216   // 96*96

typedef __attribute__((ext_vector_type(8))) short short8;
typedef __attribute__((ext_vector_type(4))) float float4v;

__device__ __forceinline__ float sigmoidf_(float x) { return 1.0f / (1.0f + expf(-x)); }

__device__ __forceinline__ short bf16rne(float f) {
  unsigned u = __builtin_bit_cast(unsigned, f);
  unsigned r = (u + 0x7FFFu + ((u >> 16) & 1u)) >> 16;
  return (short)r;
}
__device__ __forceinline__ float bf2f(short s) {
  return __builtin_bit_cast(float, ((unsigned)(unsigned short)s) << 16);
}

// ---------------------------------------------------------------------------
// Kernel W: wrap_w (192,832) fp32 -> bf16 [l][n][c]
// ---------------------------------------------------------------------------
__global__ __launch_bounds__(256) void k_wconv(const float* __restrict__ w,
                                               short* __restrict__ o)
{
  int i = blockIdx.x * 256 + threadIdx.x;
  if (i >= 192 * 832) return;
  int n = i / 832, k = i % 832;
  int l = k >> 6, c = k & 63;
  o[((size_t)l * 192 + n) * 64 + c] = bf16rne(w[i]);
}

// ---------------------------------------------------------------------------
// Kernel P: pack conv weights -> bf16 tap-GEMM layouts.
//   whK [25][32][64]  from wh (32,64,5,5)
//   wiK [7][32][32]   from wi (32,8,5,5)   (k32 = q*8+ch, tap = g*4+q, pad 0)
//   flK [25][32][32]  from fl_w (26,32,5,5) (out padded 26->32 with 0)
// grid 328 x 256 = 83968 threads total.
// ---------------------------------------------------------------------------
__global__ __launch_bounds__(256) void k_pack(
    const float* __restrict__ wh, const float* __restrict__ wi,
    const float* __restrict__ flw,
    short* __restrict__ whK, short* __restrict__ wiK, short* __restrict__ flK)
{
  int i = blockIdx.x * 256 + threadIdx.x;
  if (i < 51200) {
    int t = i / 2048, rem = i % 2048;
    int o = rem / 64, c = rem % 64;
    whK[i] = bf16rne(wh[((size_t)(o * 64 + c)) * 25 + t]);
  } else if (i < 58368) {
    int j = i - 51200;
    int g = j / 1024, rem = j % 1024;
    int o = rem / 32, k = rem % 32;
    int q = k / 8, ch = k % 8;
    int tap = g * 4 + q;
    wiK[j] = (tap < 25) ? bf16rne(wi[((size_t)(o * 8 + ch)) * 25 + tap]) : (short)0;
  } else {
    int j = i - 58368;
    int t = j / 1024, rem = j % 1024;
    int o = rem / 32, c = rem % 32;
    flK[j] = (o < 26) ? bf16rne(flw[((size_t)(o * 32 + c)) * 25 + t]) : (short)0;
  }
}

// ---------------------------------------------------------------------------
// Kernel H: state (4,64,HW) fp32 NCHW -> hbf [b][px][64] bf16 (t=0 seed)
// ---------------------------------------------------------------------------
__global__ __launch_bounds__(256) void k_h2bf(const float* __restrict__ st,
                                              short* __restrict__ hbf)
{
  const int tid = threadIdx.x;
  const int pp = tid & 63, cg = tid >> 6;
  const int b = blockIdx.y;
  const int p = blockIdx.x * 64 + pp;
  short s[16];
  #pragma unroll
  for (int k = 0; k < 16; ++k)
    s[k] = bf16rne(st[((size_t)b * 64 + cg * 16 + k) * HW + p]);
  short* dst = hbf + ((size_t)b * HW + p) * 64 + cg * 16;
  *(short8*)dst = *(short8*)&s[0];
  *(short8*)(dst + 8) = *(short8*)&s[8];
}

// ---------------------------------------------------------------------------
// Kernel X: inputs (B,T,8,HW) fp32 -> xbf [bt][px][8] bf16. grid (36,40).
// ---------------------------------------------------------------------------
__global__ __launch_bounds__(256) void k_x2bf(const float* __restrict__ inp,
                                              short* __restrict__ xbf)
{
  const int p  = blockIdx.x * 256 + threadIdx.x;
  const int bt = blockIdx.y;
  short s[8];
  #pragma unroll
  for (int ci = 0; ci < 8; ++ci)
    s[ci] = bf16rne(inp[((size_t)bt * 8 + ci) * HW + p]);
  *(short8*)(xbf + ((size_t)bt * HW + p) * 8) = *(short8*)s;
}

// ---------------------------------------------------------------------------
// Kernel A: i2h = conv3x3(x_t, 8->192, pad1) + bias -> bf16 [zz][192][HW]
// ---------------------------------------------------------------------------
__global__ __launch_bounds__(256) void k_i2h(
    const float* __restrict__ inp, int t_off,
    const float* __restrict__ w, const float* __restrict__ bias,
    short* __restrict__ out)
{
  const int p  = blockIdx.x * 256 + threadIdx.x;
  const int og = blockIdx.y;
  const int zz = blockIdx.z;
  const int t  = zz >> 2, b = zz & 3;
  const int y = p / 96, x = p % 96;
  const float* xin = inp + ((size_t)(b * 10 + t + t_off)) * 8 * HW;
  float acc[4];
  #pragma unroll
  for (int i = 0; i < 4; ++i) acc[i] = bias[og * 4 + i];
  for (int ci = 0; ci < 8; ++ci) {
    const float* xc = xin + (size_t)ci * HW;
    float v[9];
    #pragma unroll
    for (int ky = 0; ky < 3; ++ky) {
      int yy = y + ky - 1;
      bool vy = (yy >= 0) && (yy < 96);
      #pragma unroll
      for (int kx = 0; kx < 3; ++kx) {
        int xx = x + kx - 1;
        bool ok = vy && (xx >= 0) && (xx < 96);
        v[ky * 3 + kx] = ok ? xc[yy * 96 + xx] : 0.0f;
      }
    }
    #pragma unroll
    for (int i = 0; i < 4; ++i) {
      const float* wc = w + (((size_t)(og * 4 + i)) * 8 + ci) * 9;
      #pragma unroll
      for (int k = 0; k < 9; ++k) acc[i] += wc[k] * v[k];
    }
  }
  #pragma unroll
  for (int i = 0; i < 4; ++i)
    out[((size_t)(zz * 192 + og * 4 + i)) * HW + p] = bf16rne(acc[i]);
}

// ---------------------------------------------------------------------------
// Kernel B: f = tanh(conv5x5(x,8->32) + conv5x5(h,64->32) + biases) via
// tap-GEMM MFMA. grid (144,4), block 256 = 4 waves x 16 px each.
// A = shifted ch-last pixels (global 16B frags, edge-predicated),
// B = packed weights (L2-resident). D[m=px][n=out 32].
// Emits f ch-last bf16 [b][px][32].
// ---------------------------------------------------------------------------
__global__ __launch_bounds__(256) void k_f(
    const short* __restrict__ xbf, int t,
    const short* __restrict__ hbf,
    const short* __restrict__ whK,
    const short* __restrict__ wiK,
    const float* __restrict__ bi, const float* __restrict__ bh,
    short* __restrict__ fbf)
{
  const int tid = threadIdx.x;
  const int lane = tid & 63;
  const int w = tid >> 6;
  const int ml = lane & 15, qd = lane >> 4;
  const int b = blockIdx.y;
  const int px0 = blockIdx.x * 64 + w * 16;
  const int y0 = px0 / 96, xc0 = px0 % 96;   // 16 px are one row segment
  const int xcol = xc0 + ml;
  const int px = px0 + ml;
  const short* hb = hbf + (size_t)b * HW * 64;
  const short* xb = xbf + ((size_t)(b * 10 + t)) * HW * 8;

  float4v acc0 = {0.f, 0.f, 0.f, 0.f};
  float4v acc1 = {0.f, 0.f, 0.f, 0.f};

  // h-part: 25 taps x K=64
  #pragma unroll
  for (int ky = 0; ky < 5; ++ky) {
    int yy = y0 + ky - 2;
    if (yy < 0 || yy >= 96) continue;        // wave-uniform row skip
    #pragma unroll
    for (int kx = 0; kx < 5; ++kx) {
      int xx = xcol + kx - 2;
      bool cv = (xx >= 0) && (xx < 96);
      int off = (ky - 2) * 96 + (kx - 2);
      const short* ap = hb + (size_t)(px + off) * 64 + qd * 8;
      short8 a0 = {}, a1 = {};
      if (cv) { a0 = *(const short8*)ap; a1 = *(const short8*)(ap + 32); }
      int tap = ky * 5 + kx;
      const short* bp = whK + ((size_t)tap * 32 + ml) * 64 + qd * 8;
      short8 b00 = *(const short8*)bp;
      short8 b01 = *(const short8*)(bp + 32);
      short8 b10 = *(const short8*)(bp + 16 * 64);
      short8 b11 = *(const short8*)(bp + 16 * 64 + 32);
      acc0 = __builtin_amdgcn_mfma_f32_16x16x32_bf16(a0, b00, acc0, 0, 0, 0);
      acc0 = __builtin_amdgcn_mfma_f32_16x16x32_bf16(a1, b01, acc0, 0, 0, 0);
      acc1 = __builtin_amdgcn_mfma_f32_16x16x32_bf16(a0, b10, acc1, 0, 0, 0);
      acc1 = __builtin_amdgcn_mfma_f32_16x16x32_bf16(a1, b11, acc1, 0, 0, 0);
    }
  }

  // x-part: 7 groups of 4 taps (K slot qd -> tap g*4+qd, j -> x-channel)
  #pragma unroll
  for (int g = 0; g < 7; ++g) {
    int tap = g * 4 + qd;
    int dy = tap / 5 - 2;
    int dx = tap - (dy + 2) * 5 - 2;
    int yy = y0 + dy, xx = xcol + dx;
    bool v = (tap < 25) && (yy >= 0) && (yy < 96) && (xx >= 0) && (xx < 96);
    short8 a = {};
    if (v) a = *(const short8*)(xb + (size_t)(px + dy * 96 + dx) * 8);
    const short* bp = wiK + ((size_t)g * 32 + ml) * 32 + qd * 8;
    short8 b0 = *(const short8*)bp;
    short8 b1 = *(const short8*)(bp + 16 * 32);
    acc0 = __builtin_amdgcn_mfma_f32_16x16x32_bf16(a, b0, acc0, 0, 0, 0);
    acc1 = __builtin_amdgcn_mfma_f32_16x16x32_bf16(a, b1, acc1, 0, 0, 0);
  }

  // epilogue: D row m=qd*4+r (px), col n=ml (out)
  short* fo = fbf + (size_t)b * HW * 32;
  #pragma unroll
  for (int i = 0; i < 2; ++i) {
    int o = i * 16 + ml;
    float bias = bi[o] + bh[o];
    float4v a = i ? acc1 : acc0;
    #pragma unroll
    for (int r = 0; r < 4; ++r) {
      int p2 = px0 + qd * 4 + r;
      fo[(size_t)p2 * 32 + o] = bf16rne(tanhf(a[r] + bias));
    }
  }
}

// ---------------------------------------------------------------------------
// Kernel C: flows = conv5x5(f, 32->26) + bias via tap-GEMM MFMA.
// grid (144,4), block 256. Writes planar fp32 (B,26,HW).
// ---------------------------------------------------------------------------
__global__ __launch_bounds__(256) void k_flows(
    const short* __restrict__ fbf,
    const short* __restrict__ flK,
    const float* __restrict__ bias,
    float* __restrict__ fls)
{
  const int tid = threadIdx.x;
  const int lane = tid & 63;
  const int w = tid >> 6;
  const int ml = lane & 15, qd = lane >> 4;
  const int b = blockIdx.y;
  const int px0 = blockIdx.x * 64 + w * 16;
  const int y0 = px0 / 96, xc0 = px0 % 96;
  const int xcol = xc0 + ml;
  const int px = px0 + ml;
  const short* fb = fbf + (size_t)b * HW * 32;

  float4v acc0 = {0.f, 0.f, 0.f, 0.f};
  float4v acc1 = {0.f, 0.f, 0.f, 0.f};

  #pragma unroll
  for (int ky = 0; ky < 5; ++ky) {
    int yy = y0 + ky - 2;
    if (yy < 0 || yy >= 96) continue;
    #pragma unroll
    for (int kx = 0; kx < 5; ++kx) {
      int xx = xcol + kx - 2;
      bool cv = (xx >= 0) && (xx < 96);
      int off = (ky - 2) * 96 + (kx - 2);
      short8 a = {};
      if (cv) a = *(const short8*)(fb + (size_t)(px + off) * 32 + qd * 8);
      int tap = ky * 5 + kx;
      const short* bp = flK + ((size_t)tap * 32 + ml) * 32 + qd * 8;
      short8 b0 = *(const short8*)bp;
      short8 b1 = *(const short8*)(bp + 16 * 32);
      acc0 = __builtin_amdgcn_mfma_f32_16x16x32_bf16(a, b0, acc0, 0, 0, 0);
      acc1 = __builtin_amdgcn_mfma_f32_16x16x32_bf16(a, b1, acc1, 0, 0, 0);
    }
  }

  float* fo = fls + (size_t)b * 26 * HW;
  #pragma unroll
  for (int i = 0; i < 2; ++i) {
    int o = i * 16 + ml;
    if (o < 26) {
      float bv = bias[o];
      float4v a = i ? acc1 : acc0;
      #pragma unroll
      for (int r = 0; r < 4; ++r)
        fo[(size_t)o * HW + px0 + qd * 4 + r] = a[r] + bv;
    }
  }
}

// ---------------------------------------------------------------------------
// Kernel D: fused warp (channel-last bf16 h) + 1x1 conv (bf16 MFMA) + gates.
// 1-D grid 576, XCD-batch affinity swizzle. i2h read as bf16.
// ---------------------------------------------------------------------------
__global__ __launch_bounds__(256) void k_fused(
    const float* __restrict__ fls,
    const float* __restrict__ hbase, long long hstr,
    const short* __restrict__ hbf_in,
    const short* __restrict__ i2h,                // bf16 [4][192][HW] (this step)
    const short* __restrict__ wbf,
    const float* __restrict__ wb,
    float* __restrict__ outb, long long ostr,
    short* __restrict__ hbf_out,
    float* __restrict__ lastb)
{
  __shared__ __align__(16) char smem_raw[49920];
  short* lds_w = (short*)smem_raw;
  short* lds_v = lds_w + 192 * 72;
  float* lds_h = (float*)smem_raw;
  short* hpack = (short*)smem_raw;

  const int tid = threadIdx.x;
  const int pp  = tid & 63;
  const int cg  = tid >> 6;
  const int ii  = blockIdx.x;
  const int xcd = ii & 7;
  const int b   = xcd >> 1;
  const int tile = ((ii >> 3) << 1) | (xcd & 1);
  const int p   = tile * 64 + pp;
  const int ypix = p / 96, xpix = p % 96;
  const float* hb  = hbase + (size_t)b * hstr;
  const short* hvp = hbf_in + ((size_t)b * HW) * 64 + cg * 16;
  const float* flb = fls + (size_t)b * 26 * HW;
  const int ml = pp & 15;
  const int qd = pp >> 4;

  float4v acc[3][4];
  #pragma unroll
  for (int i = 0; i < 3; ++i)
    #pragma unroll
    for (int j = 0; j < 4; ++j)
      #pragma unroll
      for (int r = 0; r < 4; ++r) acc[i][j][r] = 0.0f;

  for (int l = 0; l < 13; ++l) {
    __syncthreads();
    {
      const short* wsrc = wbf + (size_t)l * 192 * 64;
      #pragma unroll
      for (int it = 0; it < 6; ++it) {
        int idx = tid + it * 256;
        int n = idx >> 3, c8 = (idx & 7) * 8;
        short8 v = *(const short8*)(wsrc + n * 64 + c8);
        *(short8*)(lds_w + n * 72 + c8) = v;
      }
    }
    float fx = flb[(size_t)(2 * l) * HW + p];
    float fy = flb[(size_t)(2 * l + 1) * HW + p];
    float vx = (float)xpix - fx;
    float vy = (float)ypix - fy;
    float gxn = 2.0f * vx / 96.0f - 1.0f;
    float gyn = 2.0f * vy / 96.0f - 1.0f;
    float ix = ((gxn + 1.0f) * 96.0f - 1.0f) * 0.5f;
    float iy = ((gyn + 1.0f) * 96.0f - 1.0f) * 0.5f;
    float x0f = floorf(ix), y0f = floorf(iy);
    float wx1 = ix - x0f, wy1 = iy - y0f;
    float wx0 = 1.0f - wx1, wy0 = 1.0f - wy1;
    int x0 = (int)x0f, y0 = (int)y0f;
    bool vx0 = (x0 >= 0) && (x0 < 96);
    bool vx1 = (x0 + 1 >= 0) && (x0 + 1 < 96);
    bool vy0g = (y0 >= 0) && (y0 < 96);
    bool vy1g = (y0 + 1 >= 0) && (y0 + 1 < 96);
    int o00 = (vx0 && vy0g) ? (y0 * 96 + x0)           : -1;
    int o01 = (vx1 && vy0g) ? (y0 * 96 + x0 + 1)       : -1;
    int o10 = (vx0 && vy1g) ? ((y0 + 1) * 96 + x0)     : -1;
    int o11 = (vx1 && vy1g) ? ((y0 + 1) * 96 + x0 + 1) : -1;
    float w00 = wy0 * wx0, w01 = wy0 * wx1, w10 = wy1 * wx0, w11 = wy1 * wx1;

    float sum[16];
    #pragma unroll
    for (int k = 0; k < 16; ++k) sum[k] = 0.0f;
    #define TAP_(off, wgt)                                            \
      if ((off) >= 0) {                                               \
        const short* tp = hvp + (size_t)(off) * 64;                   \
        short8 u0 = *(const short8*)tp;                               \
        short8 u1 = *(const short8*)(tp + 8);                         \
        _Pragma("unroll")                                             \
        for (int k = 0; k < 8; ++k) {                                 \
          sum[k]     += (wgt) * bf2f(u0[k]);                          \
          sum[k + 8] += (wgt) * bf2f(u1[k]);                          \
        }                                                             \
      }
    TAP_(o00, w00) TAP_(o01, w01) TAP_(o10, w10) TAP_(o11, w11)
    #undef TAP_
    short vv[16];
    #pragma unroll
    for (int k = 0; k < 16; ++k) vv[k] = bf16rne(sum[k]);
    *(short8*)(lds_v + pp * 72 + cg * 16)     = *(short8*)&vv[0];
    *(short8*)(lds_v + pp * 72 + cg * 16 + 8) = *(short8*)&vv[8];
    __syncthreads();

    #pragma unroll
    for (int ks = 0; ks < 2; ++ks) {
      short8 af[3], bfr[4];
      #pragma unroll
      for (int i = 0; i < 3; ++i)
        af[i] = *(const short8*)(lds_w + (48 * cg + i * 16 + ml) * 72 + ks * 32 + qd * 8);
      #pragma unroll
      for (int j = 0; j < 4; ++j)
        bfr[j] = *(const short8*)(lds_v + (j * 16 + ml) * 72 + ks * 32 + qd * 8);
      #pragma unroll
      for (int i = 0; i < 3; ++i)
        #pragma unroll
        for (int j = 0; j < 4; ++j)
          acc[i][j] = __builtin_amdgcn_mfma_f32_16x16x32_bf16(af[i], bfr[j], acc[i][j], 0, 0, 0);
    }
  }

  __syncthreads();
  #pragma unroll
  for (int i = 0; i < 3; ++i)
    #pragma unroll
    for (int j = 0; j < 4; ++j)
      #pragma unroll
      for (int r = 0; r < 4; ++r) {
        int ch = 48 * cg + i * 16 + qd * 4 + r;
        int px = j * 16 + ml;
        lds_h[ch * 65 + px] = acc[i][j][r];
      }
  __syncthreads();

  const short* i2hb = i2h + (size_t)b * 192 * HW + p;
  float* ob = outb + (size_t)b * ostr;
  float hnv[16];
  #pragma unroll
  for (int k = 0; k < 16; ++k) {
    int cch = cg + k * 4;
    float rh = lds_h[cch * 65 + pp] + wb[cch];
    float uh = lds_h[(64 + cch) * 65 + pp] + wb[64 + cch];
    float nh = lds_h[(128 + cch) * 65 + pp] + wb[128 + cch];
    float rt = bf2f(i2hb[(size_t)cch * HW]);
    float ut = bf2f(i2hb[(size_t)(64 + cch) * HW]);
    float nt = bf2f(i2hb[(size_t)(128 + cch) * HW]);
    float rr = sigmoidf_(rt + rh);
    float uu = sigmoidf_(ut + uh);
    float nn = sigmoidf_(nt + rr * nh);
    float hp = hb[(size_t)cch * HW + p];
    float hn = (1.0f - uu) * nn + uu * hp;
    ob[(size_t)cch * HW + p] = hn;
    if (lastb) lastb[((size_t)b * 64 + cch) * HW + p] = hn;
    hnv[k] = hn;
  }

  __syncthreads();
  #pragma unroll
  for (int k = 0; k < 16; ++k)
    hpack[pp * 80 + cg + 4 * k] = bf16rne(hnv[k]);
  __syncthreads();
  {
    int px = tid >> 2, g = tid & 3;
    short8 a0 = *(short8*)(hpack + px * 80 + g * 16);
    short8 a1 = *(short8*)(hpack + px * 80 + g * 16 + 8);
    short* dst = hbf_out + ((size_t)b * HW + tile * 64 + px) * 64 + g * 16;
    *(short8*)dst = a0;
    *(short8*)(dst + 8) = a1;
  }
}

// ---------------------------------------------------------------------------
extern "C" void kernel_launch(void* const* d_in, const int* in_sizes, int n_in,
                              void* d_out, int out_size, void* d_ws, size_t ws_size,
                              hipStream_t stream)
{
  const float* inp   = (const float*)d_in[0];
  const float* state = (const float*)d_in[1];
  const float* i2h_w = (const float*)d_in[2];
  const float* i2h_b = (const float*)d_in[3];
  const float* i2f_w = (const float*)d_in[4];
  const float* i2f_b = (const float*)d_in[5];
  const float* h2f_w = (const float*)d_in[6];
  const float* h2f_b = (const float*)d_in[7];
  const float* fl_w  = (const float*)d_in[8];
  const float* fl_b  = (const float*)d_in[9];
  const float* wr_w  = (const float*)d_in[10];
  const float* wr_b  = (const float*)d_in[11];
  float* out = (float*)d_out;
  float* ws  = (float*)d_ws;

  // sizes in floats
  const long long F_I2HB1 = 3538944;   // one step: 4*192*HW shorts /2
  const long long F_FBF   = 589824;    // 4*HW*32 shorts /2
  const long long F_FLS   = 958464;    // 4*26*HW fp32
  const long long F_HB    = 1179648;   // 4*HW*64 shorts /2
  const long long F_XBF   = 1474560;   // 40*HW*8 shorts /2
  const long long F_WBF   = 79872;
  const long long F_WHK   = 25600;
  const long long F_WIK   = 3584;
  const long long F_FLK   = 12800;
  const long long OB      = (long long)10 * 64 * HW;

  const long long fixed = F_FBF + F_FLS + 2 * F_HB + F_XBF + F_WBF
                        + F_WHK + F_WIK + F_FLK;
  bool batched = ws_size >= (size_t)(10 * F_I2HB1 + fixed) * 4ULL;
  long long i2h_fl = batched ? 10 * F_I2HB1 : F_I2HB1;

  short* ws_i2h = (short*)ws;
  float* fwp    = ws + i2h_fl;
  float* ws_fbf_f = fwp;              fwp += F_FBF;
  float* ws_fls   = fwp;              fwp += F_FLS;
  float* hbfA_f   = fwp;              fwp += F_HB;
  float* hbfB_f   = fwp;              fwp += F_HB;
  float* xbf_f    = fwp;              fwp += F_XBF;
  float* wbf_f    = fwp;              fwp += F_WBF;
  float* whK_f    = fwp;              fwp += F_WHK;
  float* wiK_f    = fwp;              fwp += F_WIK;
  float* flK_f    = fwp;
  short* ws_fbf = (short*)ws_fbf_f;
  short* hbfA   = (short*)hbfA_f;
  short* hbfB   = (short*)hbfB_f;
  short* ws_xbf = (short*)xbf_f;
  short* ws_wbf = (short*)wbf_f;
  short* ws_whK = (short*)whK_f;
  short* ws_wiK = (short*)wiK_f;
  short* ws_flK = (short*)flK_f;

  k_wconv<<<dim3(624), 256, 0, stream>>>(wr_w, ws_wbf);
  k_pack<<<dim3(328), 256, 0, stream>>>(h2f_w, i2f_w, fl_w, ws_whK, ws_wiK, ws_flK);
  k_h2bf<<<dim3(144, 4), 256, 0, stream>>>(state, hbfA);
  k_x2bf<<<dim3(36, 40), 256, 0, stream>>>(inp, ws_xbf);
  if (batched)
    k_i2h<<<dim3(36, 48, 40), 256, 0, stream>>>(inp, 0, i2h_w, i2h_b, ws_i2h);

  for (int t = 0; t < 10; ++t) {
    const float* hbase = (t == 0) ? state : (out + (size_t)(t - 1) * 64 * HW);
    long long hstr = (t == 0) ? (long long)64 * HW : OB;
    short* hin  = (t & 1) ? hbfB : hbfA;
    short* hout = (t & 1) ? hbfA : hbfB;

    if (!batched)
      k_i2h<<<dim3(36, 48, 4), 256, 0, stream>>>(inp, t, i2h_w, i2h_b, ws_i2h);
    k_f<<<dim3(144, 4), 256, 0, stream>>>(ws_xbf, t, hin, ws_whK, ws_wiK,
                                          i2f_b, h2f_b, ws_fbf);
    k_flows<<<dim3(144, 4), 256, 0, stream>>>(ws_fbf, ws_flK, fl_b, ws_fls);

    const short* i2h_t = batched ? (ws_i2h + (size_t)t * 2 * F_I2HB1) : ws_i2h;
    float* outbase = out + (size_t)t * 64 * HW;
    float* lastb = (t == 9) ? (out + (size_t)4 * 10 * 64 * HW) : nullptr;
    k_fused<<<dim3(576), 256, 0, stream>>>(ws_fls, hbase, hstr, hin, i2h_t,
                                           ws_wbf, wr_b, outbase, OB, hout, lastb);
  }
}